// Round 7
// baseline (2845.705 us; speedup 1.0000x reference)
//
#include <hip/hip_runtime.h>

#define FLTMAX 3.402823466e+38f

// ---------- helpers ----------
__device__ inline float b2f(unsigned short u){
    return __uint_as_float(((unsigned int)u) << 16);
}
// flag-dispatched input load: mode=1 -> f32 buffer, mode=0 -> bf16 buffer
__device__ inline float ldin(const void* p, long i, int f32m){
    return f32m ? ((const float*)p)[i] : b2f(((const unsigned short*)p)[i]);
}
__device__ inline int pix_idx(float lx, float ly, float half, int wh){
    lx = fminf(fmaxf(lx, -1.f), 1.f);
    ly = fminf(fmaxf(ly, -1.f), 1.f);
    int px = (int)rintf((lx + 1.f) * half - 0.5f);   // round-half-even = jnp.round
    int py = (int)rintf((ly + 1.f) * half - 0.5f);
    px = min(max(px, 0), wh - 1);
    py = min(max(py, 0), wh - 1);
    return py * wh + px;
}
__device__ inline void ins5(float* b5, float d){
    if(d < b5[4]){
        b5[4] = d;
#pragma unroll
        for(int q = 4; q > 0; --q){
            if(b5[q] < b5[q-1]){ float tm = b5[q]; b5[q] = b5[q-1]; b5[q-1] = tm; }
        }
    }
}
__device__ inline float wred_add(float v){
    for(int o = 32; o > 0; o >>= 1) v += __shfl_down(v, o);
    return v;
}

// ---------- dtype auto-detect ----------
__global__ __launch_bounds__(256) void detect_mode(const void* xraw, int* flag){
    __shared__ int sh[256];
    const unsigned short* p = (const unsigned short*)xraw;
    int t = threadIdx.x, c = 0;
    for(int i = t; i < 65536; i += 256){
        float v = b2f(p[i]);
        if(!(fabsf(v) < 100.f)) c++;
    }
    sh[t] = c;
    __syncthreads();
    for(int s = 128; s > 0; s >>= 1){
        if(t < s) sh[t] += sh[t + s];
        __syncthreads();
    }
    if(t == 0) flag[0] = (sh[0] > 64) ? 1 : 0;
}

// ---------- small utility kernels ----------
__global__ void fill_f32(float* p, float v, int n){
    int i = blockIdx.x * blockDim.x + threadIdx.x;
    if(i < n) p[i] = v;
}

// token2map scatter
__global__ __launch_bounds__(256) void scatter_map(const void* x, const void* loc,
                                                   const int* idx_agg, float* acc, float* cnt,
                                                   const int* mode){
    int m = *mode;
    int bn = blockIdx.x;                 // 0..16383
    int b = bn >> 12;
    float lx = ldin(loc, (long)bn * 2 + 0, m);
    float ly = ldin(loc, (long)bn * 2 + 1, m);
    int p = pix_idx(lx, ly, 32.f, 64);
    int ia = idx_agg[bn] & 4095;
    long src = ((long)(b << 12) + ia) * 256;
    float* dst = acc + ((size_t)(b << 12) + p) * 256;
    int t = threadIdx.x;                 // 256 = C
    unsafeAtomicAdd(&dst[t], ldin(x, src + t, m));
    if(t == 0) unsafeAtomicAdd(&cnt[(b << 12) + p], 1.0f);
}

__global__ void divide_map(float* xmap, const float* cnt, int n){
    int i = blockIdx.x * 256 + threadIdx.x;
    if(i < n) xmap[i] = xmap[i] / (cnt[i >> 8] + 1e-6f);
}

// ---------- GEMM: skip  (x[16384,256] @ skip_w[256,512] -> xtok f32) ----------
__global__ __launch_bounds__(256) void gemm_skip(const void* A, const void* Bw, float* C,
                                                 const int* mode){
    int m = *mode;
    __shared__ float As[16][68];
    __shared__ float Bs[16][68];
    int i0 = blockIdx.y * 64, j0 = blockIdx.x * 64;
    int t = threadIdx.x, tx = t & 15, ty = t >> 4;
    float acc[4][4] = {};
    for(int k0 = 0; k0 < 256; k0 += 16){
        int ia = t >> 2, kc = (t & 3) << 2;
#pragma unroll
        for(int u = 0; u < 4; ++u)
            As[kc+u][ia] = ldin(A, (long)(i0 + ia) * 256 + k0 + kc + u, m);
        int kb = t >> 4, jb = (t & 15) << 2;
        float4 bv;
        bv.x = ldin(Bw, (long)(k0 + kb) * 512 + j0 + jb + 0, m);
        bv.y = ldin(Bw, (long)(k0 + kb) * 512 + j0 + jb + 1, m);
        bv.z = ldin(Bw, (long)(k0 + kb) * 512 + j0 + jb + 2, m);
        bv.w = ldin(Bw, (long)(k0 + kb) * 512 + j0 + jb + 3, m);
        *(float4*)&Bs[kb][jb] = bv;
        __syncthreads();
#pragma unroll
        for(int kk = 0; kk < 16; ++kk){
            float4 a4 = *(const float4*)&As[kk][ty << 2];
            float4 b4 = *(const float4*)&Bs[kk][tx << 2];
            float ar[4] = {a4.x, a4.y, a4.z, a4.w};
            float br[4] = {b4.x, b4.y, b4.z, b4.w};
#pragma unroll
            for(int di = 0; di < 4; ++di)
#pragma unroll
                for(int dj = 0; dj < 4; ++dj)
                    acc[di][dj] = fmaf(ar[di], br[dj], acc[di][dj]);
        }
        __syncthreads();
    }
#pragma unroll
    for(int di = 0; di < 4; ++di){
        size_t i = i0 + (ty << 2) + di;
#pragma unroll
        for(int dj = 0; dj < 4; ++dj)
            C[i * 512 + j0 + (tx << 2) + dj] = acc[di][dj];
    }
}

// ---------- conv C init with bias ----------
__global__ void init_convo(float* convo, const void* bias, const int* mode){
    int m = *mode;
    int e = blockIdx.x * 256 + threadIdx.x;   // 2,097,152
    convo[e] = ldin(bias, e & 511, m);
}

// ---------- conv3x3 s2 p1 via im2col: 128x128 tile, K-split x8, atomic epilogue (r5 proven) ----------
__global__ __launch_bounds__(256) void gemm_conv(const float* xmap, const void* Bw,
                                                 float* C, const int* mode){
    int m = *mode;
    __shared__ float As[16][132];
    __shared__ float Bs[16][132];
    int i0 = blockIdx.y * 128, j0 = blockIdx.x * 128;
    int kz = blockIdx.z;                       // 0..7, K chunk of 288
    int t = threadIdx.x, tx = t & 15, ty = t >> 4;
    float acc[8][8] = {};
    for(int it = 0; it < 18; ++it){
        int k0 = kz * 288 + it * 16;
        int f = k0 >> 8;                       // tap 0..8
        int ky = f / 3, kx = f % 3;
        int c0 = k0 & 255;
        int ia = t >> 1, kc = (t & 1) << 3;    // 128 rows x 8 channels
        int p = i0 + ia;
        int b = p >> 10, r = p & 1023, oy = r >> 5, ox = r & 31;
        int iy = 2 * oy - 1 + ky, ix = 2 * ox - 1 + kx;
        float4 v0 = make_float4(0.f,0.f,0.f,0.f), v1 = v0;
        if(iy >= 0 && iy < 64 && ix >= 0 && ix < 64){
            const float* src = &xmap[((size_t)(b << 12) + (iy << 6) + ix) * 256 + c0 + kc];
            v0 = *(const float4*)src;
            v1 = *(const float4*)(src + 4);
        }
        As[kc+0][ia] = v0.x; As[kc+1][ia] = v0.y; As[kc+2][ia] = v0.z; As[kc+3][ia] = v0.w;
        As[kc+4][ia] = v1.x; As[kc+5][ia] = v1.y; As[kc+6][ia] = v1.z; As[kc+7][ia] = v1.w;
        int kb = t >> 4, jb = (t & 15) << 3;   // 16 k-rows x 128 cols
        float4 w0, w1;
        long bo = (long)(k0 + kb) * 512 + j0 + jb;
        w0.x = ldin(Bw, bo+0, m); w0.y = ldin(Bw, bo+1, m);
        w0.z = ldin(Bw, bo+2, m); w0.w = ldin(Bw, bo+3, m);
        w1.x = ldin(Bw, bo+4, m); w1.y = ldin(Bw, bo+5, m);
        w1.z = ldin(Bw, bo+6, m); w1.w = ldin(Bw, bo+7, m);
        *(float4*)&Bs[kb][jb] = w0;
        *(float4*)&Bs[kb][jb+4] = w1;
        __syncthreads();
#pragma unroll
        for(int kk = 0; kk < 16; ++kk){
            float4 a0r = *(const float4*)&As[kk][ty << 3];
            float4 a1r = *(const float4*)&As[kk][(ty << 3) + 4];
            float4 b0r = *(const float4*)&Bs[kk][tx << 2];
            float4 b1r = *(const float4*)&Bs[kk][64 + (tx << 2)];
            float ar[8] = {a0r.x, a0r.y, a0r.z, a0r.w, a1r.x, a1r.y, a1r.z, a1r.w};
            float br[8] = {b0r.x, b0r.y, b0r.z, b0r.w, b1r.x, b1r.y, b1r.z, b1r.w};
#pragma unroll
            for(int di = 0; di < 8; ++di)
#pragma unroll
                for(int dj = 0; dj < 8; ++dj)
                    acc[di][dj] = fmaf(ar[di], br[dj], acc[di][dj]);
        }
        __syncthreads();
    }
#pragma unroll
    for(int di = 0; di < 8; ++di){
        size_t i = i0 + (ty << 3) + di;
#pragma unroll
        for(int u = 0; u < 4; ++u){
            unsafeAtomicAdd(&C[i * 512 + j0 + (tx << 2) + u], acc[di][u]);
            unsafeAtomicAdd(&C[i * 512 + j0 + 64 + (tx << 2) + u], acc[di][4 + u]);
        }
    }
}

// ---------- map2token ----------
__global__ void wsum_add(const int* idx_agg, const void* aggw, float* wsum, const int* mode){
    int m = *mode;
    int e = blockIdx.x * 256 + threadIdx.x;   // 16384
    int b = e >> 12;
    unsafeAtomicAdd(&wsum[(b << 12) + (idx_agg[e] & 4095)], ldin(aggw, e, m));
}

__global__ __launch_bounds__(128) void scatter_tok(const void* loc, const int* idx_agg,
                                                   const void* aggw, const float* convo,
                                                   const float* wsum, float* xtok, const int* mode){
    int m = *mode;
    int bn = blockIdx.x;
    int b = bn >> 12;
    float lx = ldin(loc, (long)bn * 2 + 0, m);
    float ly = ldin(loc, (long)bn * 2 + 1, m);
    int p = pix_idx(lx, ly, 16.f, 32);
    int tk = idx_agg[bn] & 4095;
    float w = ldin(aggw, bn, m);
    float scale = w / wsum[(b << 12) + tk];
    const float* pv = convo + ((size_t)(b << 10) + p) * 512;
    float* dst = xtok + ((size_t)(b << 12) + tk) * 512;
    int c = threadIdx.x * 4;
    float4 v = *(const float4*)&pv[c];
    unsafeAtomicAdd(&dst[c + 0], v.x * scale);
    unsafeAtomicAdd(&dst[c + 1], v.y * scale);
    unsafeAtomicAdd(&dst[c + 2], v.z * scale);
    unsafeAtomicAdd(&dst[c + 3], v.w * scale);
}

// ---------- fused layernorm + conf + weight + x2 ----------
__global__ __launch_bounds__(128) void ln_conf(float* xtok, const void* g_, const void* b_,
                                               const void* cw_, const void* cb_,
                                               float* wgt, float* x2a, const int* mode){
    int m = *mode;
    int row = blockIdx.x;        // 0..16383
    int t = threadIdx.x;         // 128
    float* xr = xtok + (size_t)row * 512;
    int c0 = t * 4;
    float4 v = *(const float4*)&xr[c0];
    float xv[4] = {v.x, v.y, v.z, v.w};
    __shared__ float red[2];
    __shared__ float red2[4];
    float s = xv[0] + xv[1] + xv[2] + xv[3];
    s = wred_add(s);
    if((t & 63) == 0) red[t >> 6] = s;
    __syncthreads();
    float mean = (red[0] + red[1]) * (1.f / 512.f);
    __syncthreads();
    float xc[4];
#pragma unroll
    for(int u = 0; u < 4; ++u) xc[u] = xv[u] - mean;
    float q = xc[0]*xc[0] + xc[1]*xc[1] + xc[2]*xc[2] + xc[3]*xc[3];
    q = wred_add(q);
    if((t & 63) == 0) red[t >> 6] = q;
    __syncthreads();
    float var = (red[0] + red[1]) * (1.f / 512.f);
    float rs = 1.0f / sqrtf(var + 1e-5f);
    float y[4];
#pragma unroll
    for(int u = 0; u < 4; ++u)
        y[u] = xc[u] * rs * ldin(g_, c0 + u, m) + ldin(b_, c0 + u, m);
    float4 st; st.x = y[0]; st.y = y[1]; st.z = y[2]; st.w = y[3];
    *(float4*)&xr[c0] = st;
    float cf = y[0]*ldin(cw_, c0+0, m) + y[1]*ldin(cw_, c0+1, m)
             + y[2]*ldin(cw_, c0+2, m) + y[3]*ldin(cw_, c0+3, m);
    float qq = y[0]*y[0] + y[1]*y[1] + y[2]*y[2] + y[3]*y[3];
    cf = wred_add(cf);
    qq = wred_add(qq);
    if((t & 63) == 0){ red2[t >> 6] = cf; red2[2 + (t >> 6)] = qq; }
    __syncthreads();
    if(t == 0){
        wgt[row] = expf(red2[0] + red2[1] + ldin(cb_, 0, m));
        x2a[row] = red2[2] + red2[3];
    }
}

// ---------- Gram staging + MAC ----------
#define GRAM2_CORE(AROWPTR, BROWPTR)                                               \
    for(int k0 = 0; k0 < 512; k0 += 16){                                           \
        int ia = t >> 1, kc = (t & 1) << 3;                                        \
        const float* ap = (AROWPTR) + k0 + kc;                                     \
        float4 a0 = *(const float4*)ap;                                            \
        float4 a1 = *(const float4*)(ap + 4);                                      \
        As[kc+0][ia] = a0.x; As[kc+1][ia] = a0.y; As[kc+2][ia] = a0.z; As[kc+3][ia] = a0.w; \
        As[kc+4][ia] = a1.x; As[kc+5][ia] = a1.y; As[kc+6][ia] = a1.z; As[kc+7][ia] = a1.w; \
        const float* bp = (BROWPTR) + k0 + kc;                                     \
        float4 b0 = *(const float4*)bp;                                            \
        float4 b1 = *(const float4*)(bp + 4);                                      \
        Bs[kc+0][ia] = b0.x; Bs[kc+1][ia] = b0.y; Bs[kc+2][ia] = b0.z; Bs[kc+3][ia] = b0.w; \
        Bs[kc+4][ia] = b1.x; Bs[kc+5][ia] = b1.y; Bs[kc+6][ia] = b1.z; Bs[kc+7][ia] = b1.w; \
        __syncthreads();                                                           \
        for(int kk = 0; kk < 16; ++kk){                                            \
            float4 a0r = *(const float4*)&As[kk][ty << 3];                         \
            float4 a1r = *(const float4*)&As[kk][(ty << 3) + 4];                   \
            float4 b0r = *(const float4*)&Bs[kk][tx << 2];                         \
            float4 b1r = *(const float4*)&Bs[kk][64 + (tx << 2)];                  \
            float ar[8] = {a0r.x, a0r.y, a0r.z, a0r.w, a1r.x, a1r.y, a1r.z, a1r.w};\
            float br[8] = {b0r.x, b0r.y, b0r.z, b0r.w, b1r.x, b1r.y, b1r.z, b1r.w};\
            for(int di = 0; di < 8; ++di)                                          \
                for(int dj = 0; dj < 8; ++dj)                                      \
                    acc[di][dj] = fmaf(ar[di], br[dj], acc[di][dj]);               \
        }                                                                          \
        __syncthreads();                                                           \
    }

// local j of slot u (u 0..7)
#define JLOC(u) (((u) < 4) ? ((tx << 2) + (u)) : (64 + (tx << 2) + (u) - 4))

// triangular block map: q -> (bi <= bj)
#define TRI_MAP(q, bi, bj)                                         \
    int bj = (int)((sqrtf(8.0f * (q) + 1.0f) - 1.0f) * 0.5f);      \
    while((bj + 1) * (bj + 2) / 2 <= (q)) bj++;                    \
    while(bj * (bj + 1) / 2 > (q)) bj--;                           \
    int bi = (q) - bj * (bj + 1) / 2;

// ---------- COMPACT: Pass A triangular (row pass + col pass via small colbuf) ----------
__global__ __launch_bounds__(256) void gramA2(const float* Xb, const float* x2b,
                                              float* part5, float* pmax){
    __shared__ float As[16][132];
    __shared__ float Bs[16][132];
    __shared__ float colbuf[16][128];
    int z = blockIdx.z;
    TRI_MAP((int)blockIdx.x, bi, bj)
    int i0 = bi * 128, j0 = bj * 128;
    int t = threadIdx.x, tx = t & 15, ty = t >> 4;
    const float* X = Xb + (size_t)z * 2097152;
    float acc[8][8] = {};
    GRAM2_CORE(X + (size_t)(i0 + ia) * 512, X + (size_t)(j0 + ia) * 512)
    float xj[8];
#pragma unroll
    for(int u = 0; u < 8; ++u) xj[u] = x2b[(z << 12) + j0 + JLOC(u)];
    // row pass -> slot [i][bj]
#pragma unroll
    for(int di = 0; di < 8; ++di){
        int i = i0 + (ty << 3) + di;
        float xi = x2b[(z << 12) + i];
        float b5[5] = {FLTMAX, FLTMAX, FLTMAX, FLTMAX, FLTMAX};
        float mx = -FLTMAX;
#pragma unroll
        for(int u = 0; u < 8; ++u){
            float d2 = (xi + xj[u]) - 2.0f * acc[di][u];
            ins5(b5, d2);
            mx = fmaxf(mx, d2);
        }
        for(int mk = 1; mk < 16; mk <<= 1){
            float o0 = __shfl_xor(b5[0], mk), o1 = __shfl_xor(b5[1], mk),
                  o2 = __shfl_xor(b5[2], mk), o3 = __shfl_xor(b5[3], mk),
                  o4 = __shfl_xor(b5[4], mk);
            ins5(b5, o0); ins5(b5, o1); ins5(b5, o2); ins5(b5, o3); ins5(b5, o4);
            mx = fmaxf(mx, __shfl_xor(mx, mk));
        }
        if(tx == 0){
            size_t o = (((size_t)(z << 12) + i) * 32 + bj) * 5;
#pragma unroll
            for(int q = 0; q < 5; ++q) part5[o + q] = b5[q];
            pmax[((size_t)(z << 12) + i) * 32 + bj] = mx;
        }
    }
    // col pass (symmetry) -> slot [j][bi]; diagonal tiles skip (row pass covered slot)
    if(bi != bj){
        float xi8[8];
#pragma unroll
        for(int di = 0; di < 8; ++di) xi8[di] = x2b[(z << 12) + i0 + (ty << 3) + di];
        float c5[8][5];
        float cm[8];
#pragma unroll
        for(int u = 0; u < 8; ++u){
            c5[u][0] = FLTMAX; c5[u][1] = FLTMAX; c5[u][2] = FLTMAX;
            c5[u][3] = FLTMAX; c5[u][4] = FLTMAX;
            cm[u] = -FLTMAX;
#pragma unroll
            for(int di = 0; di < 8; ++di){
                float d2 = (xi8[di] + xj[u]) - 2.0f * acc[di][u];
                ins5(c5[u], d2);
                cm[u] = fmaxf(cm[u], d2);
            }
        }
        float m5[5] = {FLTMAX, FLTMAX, FLTMAX, FLTMAX, FLTMAX};
        float mm = -FLTMAX;
#pragma unroll
        for(int met = 0; met < 6; ++met){
            __syncthreads();
#pragma unroll
            for(int u = 0; u < 8; ++u)
                colbuf[ty][JLOC(u)] = (met < 5) ? c5[u][met] : cm[u];
            __syncthreads();
            if(t < 128){
                if(met < 5){
                    for(int r = 0; r < 16; ++r) ins5(m5, colbuf[r][t]);
                } else {
                    for(int r = 0; r < 16; ++r) mm = fmaxf(mm, colbuf[r][t]);
                }
            }
        }
        if(t < 128){
            size_t row = (size_t)(z << 12) + j0 + t;
            size_t o = (row * 32 + bi) * 5;
#pragma unroll
            for(int q = 0; q < 5; ++q) part5[o + q] = m5[q];
            pmax[row * 32 + bi] = mm;
        }
    }
}

__global__ __launch_bounds__(64) void reduceA2(const float* part5, const float* pmax,
                                               float* dens_b, int* dmax_b){
    int bi = blockIdx.x, t = threadIdx.x;     // bi = z*4096 + i, 0..8191
    __shared__ float l5[32][5];
    __shared__ float lm[32];
    if(t < 32){
#pragma unroll
        for(int q = 0; q < 5; ++q) l5[t][q] = part5[((size_t)bi * 32 + t) * 5 + q];
        lm[t] = pmax[(size_t)bi * 32 + t];
    }
    __syncthreads();
    if(t == 0){
        float m5[5] = {FLTMAX, FLTMAX, FLTMAX, FLTMAX, FLTMAX};
        float mm = -FLTMAX;
        for(int c = 0; c < 32; ++c){
            mm = fmaxf(mm, lm[c]);
#pragma unroll
            for(int q = 0; q < 5; ++q) ins5(m5, l5[c][q]);
        }
        const float sqrtC = 22.627416997969522f;
        float s = 0.f;
#pragma unroll
        for(int q = 0; q < 5; ++q){
            float d = sqrtf(fmaxf(m5[q], 0.f)) / sqrtC;
            s = s + d * d;
        }
        dens_b[bi] = expf(-(s / 5.0f));
        atomicMax(dmax_b + (bi >> 12), __float_as_int(fmaxf(mm, 0.f)));
    }
}

// ---------- COMPACT: Pass B triangular (masked min; row + col partials) ----------
__global__ __launch_bounds__(256) void gramB2(const float* Xb, const float* x2b,
                                              const float* dens_b, float* pmin){
    __shared__ float As[16][132];
    __shared__ float Bs[16][132];
    __shared__ float colbuf[16][128];
    int z = blockIdx.z;
    TRI_MAP((int)blockIdx.x, bi, bj)
    int i0 = bi * 128, j0 = bj * 128;
    int t = threadIdx.x, tx = t & 15, ty = t >> 4;
    const float* X = Xb + (size_t)z * 2097152;
    float acc[8][8] = {};
    GRAM2_CORE(X + (size_t)(i0 + ia) * 512, X + (size_t)(j0 + ia) * 512)
    float xj[8], dj[8];
#pragma unroll
    for(int u = 0; u < 8; ++u){
        int j = j0 + JLOC(u);
        xj[u] = x2b[(z << 12) + j];
        dj[u] = dens_b[(z << 12) + j];
    }
    // row pass -> slot [i][bj]
#pragma unroll
    for(int di = 0; di < 8; ++di){
        int i = i0 + (ty << 3) + di;
        float xi = x2b[(z << 12) + i];
        float deni = dens_b[(z << 12) + i];
        float pm = FLTMAX;
#pragma unroll
        for(int u = 0; u < 8; ++u){
            if(dj[u] > deni){
                float d2 = (xi + xj[u]) - 2.0f * acc[di][u];
                pm = fminf(pm, d2);
            }
        }
        for(int mk = 1; mk < 16; mk <<= 1)
            pm = fminf(pm, __shfl_xor(pm, mk));
        if(tx == 0) pmin[((size_t)(z << 12) + i) * 32 + bj] = pm;
    }
    // col pass (symmetry) -> slot [j][bi]
    if(bi != bj){
        float xi8[8], di8[8];
#pragma unroll
        for(int di = 0; di < 8; ++di){
            int i = i0 + (ty << 3) + di;
            xi8[di] = x2b[(z << 12) + i];
            di8[di] = dens_b[(z << 12) + i];
        }
        __syncthreads();
#pragma unroll
        for(int u = 0; u < 8; ++u){
            float denj = dj[u];
            float pm = FLTMAX;
#pragma unroll
            for(int di = 0; di < 8; ++di){
                if(di8[di] > denj){
                    float d2 = (xi8[di] + xj[u]) - 2.0f * acc[di][u];
                    pm = fminf(pm, d2);
                }
            }
            colbuf[ty][JLOC(u)] = pm;
        }
        __syncthreads();
        if(t < 128){
            float m = FLTMAX;
            for(int r = 0; r < 16; ++r) m = fminf(m, colbuf[r][t]);
            pmin[((size_t)(z << 12) + j0 + t) * 32 + bi] = m;
        }
    }
}

__global__ __launch_bounds__(64) void reduceB2(const float* pmin, const float* dens_b,
                                               const int* dmax_b, float* score_b){
    int bi = blockIdx.x, t = threadIdx.x;     // 0..8191
    __shared__ float lm[32];
    if(t < 32) lm[t] = pmin[(size_t)bi * 32 + t];
    __syncthreads();
    if(t == 0){
        float m = FLTMAX;
        for(int c = 0; c < 32; ++c) m = fminf(m, lm[c]);
        const float sqrtC = 22.627416997969522f;
        float dp;
        if(m == FLTMAX) dp = sqrtf(fmaxf(__int_as_float(dmax_b[bi >> 12]), 0.f)) / sqrtC;
        else            dp = sqrtf(fmaxf(m, 0.f)) / sqrtC;
        score_b[bi] = dp * dens_b[bi];
    }
}

// ---------- COMPACT: Pass C (gathered centers, full grid — r5 proven) ----------
__global__ __launch_bounds__(256) void gramC2(const float* Xb, const float* x2b,
                                              const int* idown_b, float* pcd, int* pci){
    __shared__ float As[16][132];
    __shared__ float Bs[16][132];
    __shared__ float ldd[16][128];
    __shared__ int   ldi[16][128];
    int z = blockIdx.z;
    int s0 = blockIdx.y * 128, j0 = blockIdx.x * 128;
    int t = threadIdx.x, tx = t & 15, ty = t >> 4;
    const float* X = Xb + (size_t)z * 2097152;
    const int* idz = idown_b + (z << 10);
    float acc[8][8] = {};
    GRAM2_CORE(X + (size_t)idz[s0 + ia] * 512, X + (size_t)(j0 + ia) * 512)
    const float sqrtC = 22.627416997969522f;
    float xc[8];
#pragma unroll
    for(int di = 0; di < 8; ++di) xc[di] = x2b[(z << 12) + idz[s0 + (ty << 3) + di]];
#pragma unroll
    for(int u = 0; u < 8; ++u){
        int jl = JLOC(u);
        float xj = x2b[(z << 12) + j0 + jl];
        float bd = FLTMAX;
        int bs = 0;
#pragma unroll
        for(int di = 0; di < 8; ++di){           // di ascending => first-min ties stay first
            float d2 = (xc[di] + xj) - 2.0f * acc[di][u];
            float d = sqrtf(fmaxf(d2, 0.f)) / sqrtC;
            if(d < bd){ bd = d; bs = s0 + (ty << 3) + di; }
        }
        ldd[ty][jl] = bd;
        ldi[ty][jl] = bs;
    }
    __syncthreads();
    if(t < 128){
        float bd = FLTMAX;
        int bs = 0;
        for(int r = 0; r < 16; ++r){              // r ascending => center index ascending
            float d = ldd[r][t];
            if(d < bd){ bd = d; bs = ldi[r][t]; }
        }
        pcd[((size_t)(z << 12) + j0 + t) * 8 + blockIdx.y] = bd;
        pci[((size_t)(z << 12) + j0 + t) * 8 + blockIdx.y] = bs;
    }
}

__global__ void reduceC2(const float* pcd, const int* pci, int* iclus_b){
    int jg = blockIdx.x * 256 + threadIdx.x;      // 0..8191
    float bd = FLTMAX;
    int bs = 0;
    for(int c = 0; c < 8; ++c){
        float d = pcd[(size_t)jg * 8 + c];
        if(d < bd){ bd = d; bs = pci[(size_t)jg * 8 + c]; }
    }
    iclus_b[jg] = bs;
}

// ---------- FAST-path kernels (full grid — r5 proven) ----------
__global__ __launch_bounds__(256) void gemm_gram(const float* X, const float* x2, float* dist){
    __shared__ float As[16][132];
    __shared__ float Bs[16][132];
    int i0 = blockIdx.y * 128, j0 = blockIdx.x * 128;
    int t = threadIdx.x, tx = t & 15, ty = t >> 4;
    float acc[8][8] = {};
    GRAM2_CORE(X + (size_t)(i0 + ia) * 512, X + (size_t)(j0 + ia) * 512)
    const float sqrtC = 22.627416997969522f;
#pragma unroll
    for(int di = 0; di < 8; ++di){
        int i = i0 + (ty << 3) + di;
        float xi = x2[i];
#pragma unroll
        for(int u = 0; u < 8; ++u){
            int j = j0 + JLOC(u);
            float d2 = (xi + x2[j]) - 2.0f * acc[di][u];
            dist[(size_t)i * 4096 + j] = sqrtf(fmaxf(d2, 0.f)) / sqrtC;
        }
    }
}

__global__ __launch_bounds__(256) void knn_density(const float* dist, float* dens, int* dmax_i){
    int i = blockIdx.x, t = threadIdx.x;
    const float* row = dist + (size_t)i * 4096;
    float best[5] = {FLTMAX, FLTMAX, FLTMAX, FLTMAX, FLTMAX};
    float mx = 0.f;
    for(int j = t; j < 4096; j += 256){
        float d = row[j];
        mx = fmaxf(mx, d);
        ins5(best, d);
    }
    __shared__ float lb[256 * 5];
    __shared__ float r4[4];
#pragma unroll
    for(int q = 0; q < 5; ++q) lb[t * 5 + q] = best[q];
    float wm = mx;
    for(int o = 32; o > 0; o >>= 1) wm = fmaxf(wm, __shfl_down(wm, o));
    if((t & 63) == 0) r4[t >> 6] = wm;
    __syncthreads();
    for(int nl = 64; nl >= 1; nl >>= 2){
        float mg[5] = {FLTMAX, FLTMAX, FLTMAX, FLTMAX, FLTMAX};
        if(t < nl){
            for(int l = 0; l < 4; ++l){
                int base = (t * 4 + l) * 5;
#pragma unroll
                for(int q = 0; q < 5; ++q) ins5(mg, lb[base + q]);
            }
        }
        __syncthreads();
        if(t < nl){
#pragma unroll
            for(int q = 0; q < 5; ++q) lb[t * 5 + q] = mg[q];
        }
        __syncthreads();
    }
    if(t == 0){
        float s = 0.f;
#pragma unroll
        for(int q = 0; q < 5; ++q){ float d = lb[q]; s = s + d * d; }
        dens[i] = expf(-(s / 5.0f));
        float bm = fmaxf(fmaxf(r4[0], r4[1]), fmaxf(r4[2], r4[3]));
        atomicMax(dmax_i, __float_as_int(bm));
    }
}

__global__ __launch_bounds__(256) void parent_score(const float* dist, const float* dens,
                                                    const int* dmax_i, float* score){
    int i = blockIdx.x, t = threadIdx.x;
    float di = dens[i];
    const float* row = dist + (size_t)i * 4096;
    float m = FLTMAX;
    for(int j = t; j < 4096; j += 256){
        float dj = dens[j];
        float d = row[j];
        if(dj > di) m = fminf(m, d);
    }
    for(int o = 32; o > 0; o >>= 1) m = fminf(m, __shfl_down(m, o));
    __shared__ float r4[4];
    if((t & 63) == 0) r4[t >> 6] = m;
    __syncthreads();
    if(t == 0){
        float mm = fminf(fminf(r4[0], r4[1]), fminf(r4[2], r4[3]));
        if(mm == FLTMAX) mm = __int_as_float(*dmax_i);
        score[i] = mm * di;
    }
}

__global__ __launch_bounds__(256) void assign_k(const float* dist, const int* idown, int* iclus){
    __shared__ int cs[1024];
    int t = threadIdx.x;
    for(int v = t; v < 1024; v += 256) cs[v] = idown[v];
    __syncthreads();
    int i = blockIdx.x * 256 + t;
    float bd = FLTMAX;
    int bs = 0;
    for(int s = 0; s < 1024; ++s){
        float d = dist[(size_t)cs[s] * 4096 + i];
        if(d < bd){ bd = d; bs = s; }
    }
    iclus[i] = bs;
}

// ---------- bitonic sort (score desc, idx asc) -> top 1024; blockIdx.x = batch ----------
__global__ __launch_bounds__(1024) void sort_topk(const float* score, int* idown){
    __shared__ float ss[4096];
    __shared__ int sid[4096];
    int t = threadIdx.x;
    const float* sc = score + (size_t)blockIdx.x * 4096;
    int* id = idown + (size_t)blockIdx.x * 1024;
    for(int v = t; v < 4096; v += 1024){ ss[v] = sc[v]; sid[v] = v; }
    __syncthreads();
    for(int k = 2; k <= 4096; k <<= 1){
        for(int j = k >> 1; j > 0; j >>= 1){
            for(int v = t; v < 4096; v += 1024){
                int l = v ^ j;
                if(l > v){
                    float sv = ss[v], sl = ss[l];
                    int iv = sid[v], il = sid[l];
                    bool before_lv = (sl > sv) || (sl == sv && il < iv);
                    bool before_vl = (sv > sl) || (sv == sl && iv < il);
                    bool asc = ((v & k) == 0);
                    bool sw = asc ? before_lv : before_vl;
                    if(sw){ ss[v] = sl; ss[l] = sv; sid[v] = il; sid[l] = iv; }
                }
            }
            __syncthreads();
        }
    }
    for(int v = t; v < 1024; v += 1024) id[v] = sid[v];
}

// ---------- merge tokens + outputs (FLOAT32 out) ----------
__global__ void allw_add(const int* iclus, const float* wgt, float* allw){
    int e = blockIdx.x * 256 + threadIdx.x;   // 16384
    int b = e >> 12;
    unsafeAtomicAdd(&allw[(b << 10) + (iclus[e] & 1023)], wgt[e]);
}
__global__ void norm_k(const int* iclus, const float* wgt, const float* allw, float* nw){
    int e = blockIdx.x * 256 + threadIdx.x;
    int b = e >> 12;
    nw[e] = wgt[e] / allw[(b << 10) + (iclus[e] & 1023)];
}
__global__ void abuf_k(const int* idx_agg, const void* aggw, const float* nw,
                       float* abuf, float* maxw, const int* mode){
    int m = *mode;
    int e = blockIdx.x * 256 + threadIdx.x;
    int b = e >> 12;
    float a = ldin(aggw, e, m) * nw[(b << 12) + (idx_agg[e] & 4095)];
    abuf[e] = a;
    atomicMax((int*)&maxw[b], __float_as_int(a));
}
__global__ __launch_bounds__(128) void scatter_xdown(const int* iclus, const float* nw,
                                                     const float* xtok, float* xdown){
    int bn = blockIdx.x;           // 0..16383
    int b = bn >> 12;
    int cl = iclus[bn] & 1023;
    float w = nw[bn];
    const float* src = xtok + (size_t)bn * 512;
    float* dst = xdown + ((size_t)(b << 10) + cl) * 512;
    int c = threadIdx.x * 4;
    float4 v = *(const float4*)&src[c];
    unsafeAtomicAdd(&dst[c + 0], v.x * w);
    unsafeAtomicAdd(&dst[c + 1], v.y * w);
    unsafeAtomicAdd(&dst[c + 2], v.z * w);
    unsafeAtomicAdd(&dst[c + 3], v.w * w);
}

__global__ void out0_k(const float* xdown, float* out){
    int e = blockIdx.x * 256 + threadIdx.x;
    if(e < 2097152) out[e] = xdown[e];
}
__global__ void out1_k(const int* idx_agg, const int* iclus, float* out){
    int e = blockIdx.x * 256 + threadIdx.x;   // 16384
    int b = e >> 12;
    int ic = iclus[(b << 12) + (idx_agg[e] & 4095)];
    out[e] = (float)ic;
}
__global__ void out2_k(const float* abuf, const float* maxw, float* out){
    int e = blockIdx.x * 256 + threadIdx.x;
    int b = e >> 12;
    out[e] = abuf[e] / maxw[b];
}

// ---------- launch ----------
extern "C" void kernel_launch(void* const* d_in, const int* in_sizes, int n_in,
                              void* d_out, int out_size, void* d_ws, size_t ws_size,
                              hipStream_t stream){
    (void)in_sizes; (void)n_in; (void)out_size;
    const void* x    = d_in[0];
    const void* loc  = d_in[1];
    const int* idx_agg = (const int*)d_in[2];
    const void* aggw = d_in[3];
    const void* cw   = d_in[7];
    const void* cb   = d_in[8];
    const void* sw   = d_in[9];
    const void* lg   = d_in[10];
    const void* lnb  = d_in[11];
    const void* cfw  = d_in[12];
    const void* cfb  = d_in[13];
    float* out = (float*)d_out;

    float* ws = (float*)d_ws;
    const bool fast = ws_size >= (size_t)101154852;

    float *xmap, *cnt, *convo, *xtok, *xdown, *dist = nullptr;
    float *part5, *pmaxb, *pminb, *pcd;
    int *pci;
    float *x2, *wgt, *dens, *score, *wsum, *allw, *nw, *dmaxf, *maxw;
    int *idown, *iclus, *mode;

    if(fast){
        dist  = ws;
        xmap  = ws;
        cnt   = ws + 4194304;
        convo = ws + 4210688;
        xdown = ws + 6307840;
        xtok  = ws + 16777216;
        x2    = ws + 25165824;
        wgt   = ws + 25182208;
        dens  = ws + 25198592;
        score = ws + 25214976;
        wsum  = ws + 25231360;
        allw  = ws + 25247744;
        nw    = ws + 25251840;
        dmaxf = ws + 25268224;
        maxw  = ws + 25268228;
        idown = (int*)(ws + 25268232);
        iclus = (int*)(ws + 25272328);
        mode  = (int*)(ws + 25288712);
        part5 = pmaxb = pminb = pcd = nullptr; pci = nullptr;
    } else {
        xtok  = ws;                       // xmap unions [0, 4,194,304)
        xmap  = ws;
        cnt   = ws + 8388608;
        float* U = ws + 8404992;          // 2,097,152-float union region
        convo = U;                        // phase 1
        part5 = U;                        // phase 2: 2 batches x 4096 x 32 x 5 = 1,310,720
        pmaxb = U + 1310720;              // 262,144
        pminb = U + 1572864;              // 262,144
        pcd   = U + 1835008;              // 65,536
        pci   = (int*)(U + 1900544);      // 65,536 -> ends 1,966,080
        xdown = U;                        // phase 3
        x2    = ws + 10502144;
        wgt   = ws + 10518528;
        dens  = ws + 10534912;
        score = ws + 10551296;
        wsum  = ws + 10567680;
        allw  = ws + 10584064;
        nw    = ws + 10588160;
        dmaxf = ws + 10604544;
        maxw  = ws + 10604548;
        idown = (int*)(ws + 10604552);
        iclus = (int*)(ws + 10608648);
        mode  = (int*)(ws + 10625032);
    }

    detect_mode<<<1, 256, 0, stream>>>(x, mode);

    hipMemsetAsync(xmap, 0, (size_t)4194304 * 4, stream);
    hipMemsetAsync(cnt, 0, (size_t)16384 * 4, stream);
    hipMemsetAsync(dmaxf, 0, 8 * 4, stream);
    fill_f32<<<64, 256, 0, stream>>>(wsum, 1e-6f, 16384);
    fill_f32<<<16, 256, 0, stream>>>(allw, 1e-6f, 4096);

    scatter_map<<<16384, 256, 0, stream>>>(x, loc, idx_agg, xmap, cnt, mode);
    divide_map<<<16384, 256, 0, stream>>>(xmap, cnt, 4194304);

    init_convo<<<8192, 256, 0, stream>>>(convo, cb, mode);
    gemm_conv<<<dim3(4, 32, 8), 256, 0, stream>>>(xmap, cw, convo, mode);    // xmap dies here
    gemm_skip<<<dim3(8, 256), 256, 0, stream>>>(x, sw, xtok, mode);          // may overwrite xmap region

    wsum_add<<<64, 256, 0, stream>>>(idx_agg, aggw, wsum, mode);
    scatter_tok<<<16384, 128, 0, stream>>>(loc, idx_agg, aggw, convo, wsum, xtok, mode);
    ln_conf<<<16384, 128, 0, stream>>>(xtok, lg, lnb, cfw, cfb, wgt, x2, mode);

    if(fast){
        for(int b = 0; b < 4; ++b){
            const float* X  = xtok + (size_t)b * 2097152;
            const float* xb = x2 + b * 4096;
            float* db = dens + b * 4096;
            float* sb = score + b * 4096;
            int* ib   = idown + b * 1024;
            int* cbp  = iclus + b * 4096;
            int* dm   = (int*)dmaxf + b;
            gemm_gram<<<dim3(32, 32), 256, 0, stream>>>(X, xb, dist);
            knn_density<<<4096, 256, 0, stream>>>(dist, db, dm);
            parent_score<<<4096, 256, 0, stream>>>(dist, db, dm, sb);
            sort_topk<<<1, 1024, 0, stream>>>(sb, ib);
            assign_k<<<16, 256, 0, stream>>>(dist, ib, cbp);
        }
    } else {
        for(int zb = 0; zb < 4; zb += 2){
            const float* Xb  = xtok + (size_t)zb * 2097152;
            const float* x2b = x2 + zb * 4096;
            float* db = dens + zb * 4096;
            float* sb = score + zb * 4096;
            int* ib   = idown + zb * 1024;
            int* cbp  = iclus + zb * 4096;
            int* dm   = (int*)dmaxf + zb;
            gramA2<<<dim3(528, 1, 2), 256, 0, stream>>>(Xb, x2b, part5, pmaxb);
            reduceA2<<<8192, 64, 0, stream>>>(part5, pmaxb, db, dm);
            gramB2<<<dim3(528, 1, 2), 256, 0, stream>>>(Xb, x2b, db, pminb);
            reduceB2<<<8192, 64, 0, stream>>>(pminb, db, dm, sb);
            sort_topk<<<2, 1024, 0, stream>>>(sb, ib);
            gramC2<<<dim3(32, 8, 2), 256, 0, stream>>>(Xb, x2b, ib, pcd, pci);
            reduceC2<<<32, 256, 0, stream>>>(pcd, pci, cbp);
        }
    }

    allw_add<<<64, 256, 0, stream>>>(iclus, wgt, allw);
    norm_k<<<64, 256, 0, stream>>>(iclus, wgt, allw, nw);
    abuf_k<<<64, 256, 0, stream>>>(idx_agg, aggw, nw, score, maxw, mode);   // score reused as abuf

    hipMemsetAsync(xdown, 0, (size_t)2097152 * 4, stream);                  // after batch loop (aliasing)
    scatter_xdown<<<16384, 128, 0, stream>>>(iclus, nw, xtok, xdown);

    out0_k<<<8192, 256, 0, stream>>>(xdown, out);
    out1_k<<<64, 256, 0, stream>>>(idx_agg, iclus, out + 2097152);
    out2_k<<<64, 256, 0, stream>>>(score, maxw, out + 2097152 + 16384);
}

// Round 8
// 2433.473 us; speedup vs baseline: 1.1694x; 1.1694x over previous
//
#include <hip/hip_runtime.h>

#define FLTMAX 3.402823466e+38f

// ---------- helpers ----------
__device__ inline float b2f(unsigned short u){
    return __uint_as_float(((unsigned int)u) << 16);
}
// flag-dispatched input load: mode=1 -> f32 buffer, mode=0 -> bf16 buffer
__device__ inline float ldin(const void* p, long i, int f32m){
    return f32m ? ((const float*)p)[i] : b2f(((const unsigned short*)p)[i]);
}
__device__ inline int pix_idx(float lx, float ly, float half, int wh){
    lx = fminf(fmaxf(lx, -1.f), 1.f);
    ly = fminf(fmaxf(ly, -1.f), 1.f);
    int px = (int)rintf((lx + 1.f) * half - 0.5f);   // round-half-even = jnp.round
    int py = (int)rintf((ly + 1.f) * half - 0.5f);
    px = min(max(px, 0), wh - 1);
    py = min(max(py, 0), wh - 1);
    return py * wh + px;
}
__device__ inline void ins5(float* b5, float d){
    if(d < b5[4]){
        b5[4] = d;
#pragma unroll
        for(int q = 4; q > 0; --q){
            if(b5[q] < b5[q-1]){ float tm = b5[q]; b5[q] = b5[q-1]; b5[q-1] = tm; }
        }
    }
}
__device__ inline float wred_add(float v){
    for(int o = 32; o > 0; o >>= 1) v += __shfl_down(v, o);
    return v;
}

// ---------- dtype auto-detect ----------
__global__ __launch_bounds__(256) void detect_mode(const void* xraw, int* flag){
    __shared__ int sh[256];
    const unsigned short* p = (const unsigned short*)xraw;
    int t = threadIdx.x, c = 0;
    for(int i = t; i < 65536; i += 256){
        float v = b2f(p[i]);
        if(!(fabsf(v) < 100.f)) c++;
    }
    sh[t] = c;
    __syncthreads();
    for(int s = 128; s > 0; s >>= 1){
        if(t < s) sh[t] += sh[t + s];
        __syncthreads();
    }
    if(t == 0) flag[0] = (sh[0] > 64) ? 1 : 0;
}

// ---------- small utility kernels ----------
__global__ void fill_f32(float* p, float v, int n){
    int i = blockIdx.x * blockDim.x + threadIdx.x;
    if(i < n) p[i] = v;
}

// token2map scatter
__global__ __launch_bounds__(256) void scatter_map(const void* x, const void* loc,
                                                   const int* idx_agg, float* acc, float* cnt,
                                                   const int* mode){
    int m = *mode;
    int bn = blockIdx.x;                 // 0..16383
    int b = bn >> 12;
    float lx = ldin(loc, (long)bn * 2 + 0, m);
    float ly = ldin(loc, (long)bn * 2 + 1, m);
    int p = pix_idx(lx, ly, 32.f, 64);
    int ia = idx_agg[bn] & 4095;
    long src = ((long)(b << 12) + ia) * 256;
    float* dst = acc + ((size_t)(b << 12) + p) * 256;
    int t = threadIdx.x;                 // 256 = C
    unsafeAtomicAdd(&dst[t], ldin(x, src + t, m));
    if(t == 0) unsafeAtomicAdd(&cnt[(b << 12) + p], 1.0f);
}

__global__ void divide_map(float* xmap, const float* cnt, int n){
    int i = blockIdx.x * 256 + threadIdx.x;
    if(i < n) xmap[i] = xmap[i] / (cnt[i >> 8] + 1e-6f);
}

// ---------- GEMM: skip  (x[16384,256] @ skip_w[256,512] -> xtok f32) ----------
__global__ __launch_bounds__(256) void gemm_skip(const void* A, const void* Bw, float* C,
                                                 const int* mode){
    int m = *mode;
    __shared__ float As[16][68];
    __shared__ float Bs[16][68];
    int i0 = blockIdx.y * 64, j0 = blockIdx.x * 64;
    int t = threadIdx.x, tx = t & 15, ty = t >> 4;
    float acc[4][4] = {};
    for(int k0 = 0; k0 < 256; k0 += 16){
        int ia = t >> 2, kc = (t & 3) << 2;
#pragma unroll
        for(int u = 0; u < 4; ++u)
            As[kc+u][ia] = ldin(A, (long)(i0 + ia) * 256 + k0 + kc + u, m);
        int kb = t >> 4, jb = (t & 15) << 2;
        float4 bv;
        bv.x = ldin(Bw, (long)(k0 + kb) * 512 + j0 + jb + 0, m);
        bv.y = ldin(Bw, (long)(k0 + kb) * 512 + j0 + jb + 1, m);
        bv.z = ldin(Bw, (long)(k0 + kb) * 512 + j0 + jb + 2, m);
        bv.w = ldin(Bw, (long)(k0 + kb) * 512 + j0 + jb + 3, m);
        *(float4*)&Bs[kb][jb] = bv;
        __syncthreads();
#pragma unroll
        for(int kk = 0; kk < 16; ++kk){
            float4 a4 = *(const float4*)&As[kk][ty << 2];
            float4 b4 = *(const float4*)&Bs[kk][tx << 2];
            float ar[4] = {a4.x, a4.y, a4.z, a4.w};
            float br[4] = {b4.x, b4.y, b4.z, b4.w};
#pragma unroll
            for(int di = 0; di < 4; ++di)
#pragma unroll
                for(int dj = 0; dj < 4; ++dj)
                    acc[di][dj] = fmaf(ar[di], br[dj], acc[di][dj]);
        }
        __syncthreads();
    }
#pragma unroll
    for(int di = 0; di < 4; ++di){
        size_t i = i0 + (ty << 2) + di;
#pragma unroll
        for(int dj = 0; dj < 4; ++dj)
            C[i * 512 + j0 + (tx << 2) + dj] = acc[di][dj];
    }
}

// ---------- conv C init with bias ----------
__global__ void init_convo(float* convo, const void* bias, const int* mode){
    int m = *mode;
    int e = blockIdx.x * 256 + threadIdx.x;   // 2,097,152
    convo[e] = ldin(bias, e & 511, m);
}

// ---------- conv3x3 s2 p1 via im2col: 128x128 tile, K-split x8, atomic epilogue ----------
__global__ __launch_bounds__(256) void gemm_conv(const float* xmap, const void* Bw,
                                                 float* C, const int* mode){
    int m = *mode;
    __shared__ float As[16][132];
    __shared__ float Bs[16][132];
    int i0 = blockIdx.y * 128, j0 = blockIdx.x * 128;
    int kz = blockIdx.z;                       // 0..7, K chunk of 288
    int t = threadIdx.x, tx = t & 15, ty = t >> 4;
    float acc[8][8] = {};
    for(int it = 0; it < 18; ++it){
        int k0 = kz * 288 + it * 16;
        int f = k0 >> 8;                       // tap 0..8
        int ky = f / 3, kx = f % 3;
        int c0 = k0 & 255;
        int ia = t >> 1, kc = (t & 1) << 3;    // 128 rows x 8 channels
        int p = i0 + ia;
        int b = p >> 10, r = p & 1023, oy = r >> 5, ox = r & 31;
        int iy = 2 * oy - 1 + ky, ix = 2 * ox - 1 + kx;
        float4 v0 = make_float4(0.f,0.f,0.f,0.f), v1 = v0;
        if(iy >= 0 && iy < 64 && ix >= 0 && ix < 64){
            const float* src = &xmap[((size_t)(b << 12) + (iy << 6) + ix) * 256 + c0 + kc];
            v0 = *(const float4*)src;
            v1 = *(const float4*)(src + 4);
        }
        As[kc+0][ia] = v0.x; As[kc+1][ia] = v0.y; As[kc+2][ia] = v0.z; As[kc+3][ia] = v0.w;
        As[kc+4][ia] = v1.x; As[kc+5][ia] = v1.y; As[kc+6][ia] = v1.z; As[kc+7][ia] = v1.w;
        int kb = t >> 4, jb = (t & 15) << 3;   // 16 k-rows x 128 cols
        float4 w0, w1;
        long bo = (long)(k0 + kb) * 512 + j0 + jb;
        w0.x = ldin(Bw, bo+0, m); w0.y = ldin(Bw, bo+1, m);
        w0.z = ldin(Bw, bo+2, m); w0.w = ldin(Bw, bo+3, m);
        w1.x = ldin(Bw, bo+4, m); w1.y = ldin(Bw, bo+5, m);
        w1.z = ldin(Bw, bo+6, m); w1.w = ldin(Bw, bo+7, m);
        *(float4*)&Bs[kb][jb] = w0;
        *(float4*)&Bs[kb][jb+4] = w1;
        __syncthreads();
#pragma unroll
        for(int kk = 0; kk < 16; ++kk){
            float4 a0r = *(const float4*)&As[kk][ty << 3];
            float4 a1r = *(const float4*)&As[kk][(ty << 3) + 4];
            float4 b0r = *(const float4*)&Bs[kk][tx << 2];
            float4 b1r = *(const float4*)&Bs[kk][64 + (tx << 2)];
            float ar[8] = {a0r.x, a0r.y, a0r.z, a0r.w, a1r.x, a1r.y, a1r.z, a1r.w};
            float br[8] = {b0r.x, b0r.y, b0r.z, b0r.w, b1r.x, b1r.y, b1r.z, b1r.w};
#pragma unroll
            for(int di = 0; di < 8; ++di)
#pragma unroll
                for(int dj = 0; dj < 8; ++dj)
                    acc[di][dj] = fmaf(ar[di], br[dj], acc[di][dj]);
        }
        __syncthreads();
    }
#pragma unroll
    for(int di = 0; di < 8; ++di){
        size_t i = i0 + (ty << 3) + di;
#pragma unroll
        for(int u = 0; u < 4; ++u){
            unsafeAtomicAdd(&C[i * 512 + j0 + (tx << 2) + u], acc[di][u]);
            unsafeAtomicAdd(&C[i * 512 + j0 + 64 + (tx << 2) + u], acc[di][4 + u]);
        }
    }
}

// ---------- map2token ----------
__global__ void wsum_add(const int* idx_agg, const void* aggw, float* wsum, const int* mode){
    int m = *mode;
    int e = blockIdx.x * 256 + threadIdx.x;   // 16384
    int b = e >> 12;
    unsafeAtomicAdd(&wsum[(b << 12) + (idx_agg[e] & 4095)], ldin(aggw, e, m));
}

__global__ __launch_bounds__(128) void scatter_tok(const void* loc, const int* idx_agg,
                                                   const void* aggw, const float* convo,
                                                   const float* wsum, float* xtok, const int* mode){
    int m = *mode;
    int bn = blockIdx.x;
    int b = bn >> 12;
    float lx = ldin(loc, (long)bn * 2 + 0, m);
    float ly = ldin(loc, (long)bn * 2 + 1, m);
    int p = pix_idx(lx, ly, 16.f, 32);
    int tk = idx_agg[bn] & 4095;
    float w = ldin(aggw, bn, m);
    float scale = w / wsum[(b << 12) + tk];
    const float* pv = convo + ((size_t)(b << 10) + p) * 512;
    float* dst = xtok + ((size_t)(b << 12) + tk) * 512;
    int c = threadIdx.x * 4;
    float4 v = *(const float4*)&pv[c];
    unsafeAtomicAdd(&dst[c + 0], v.x * scale);
    unsafeAtomicAdd(&dst[c + 1], v.y * scale);
    unsafeAtomicAdd(&dst[c + 2], v.z * scale);
    unsafeAtomicAdd(&dst[c + 3], v.w * scale);
}

// ---------- fused layernorm + conf + weight + x2 ----------
__global__ __launch_bounds__(128) void ln_conf(float* xtok, const void* g_, const void* b_,
                                               const void* cw_, const void* cb_,
                                               float* wgt, float* x2a, const int* mode){
    int m = *mode;
    int row = blockIdx.x;        // 0..16383
    int t = threadIdx.x;         // 128
    float* xr = xtok + (size_t)row * 512;
    int c0 = t * 4;
    float4 v = *(const float4*)&xr[c0];
    float xv[4] = {v.x, v.y, v.z, v.w};
    __shared__ float red[2];
    __shared__ float red2[4];
    float s = xv[0] + xv[1] + xv[2] + xv[3];
    s = wred_add(s);
    if((t & 63) == 0) red[t >> 6] = s;
    __syncthreads();
    float mean = (red[0] + red[1]) * (1.f / 512.f);
    __syncthreads();
    float xc[4];
#pragma unroll
    for(int u = 0; u < 4; ++u) xc[u] = xv[u] - mean;
    float q = xc[0]*xc[0] + xc[1]*xc[1] + xc[2]*xc[2] + xc[3]*xc[3];
    q = wred_add(q);
    if((t & 63) == 0) red[t >> 6] = q;
    __syncthreads();
    float var = (red[0] + red[1]) * (1.f / 512.f);
    float rs = 1.0f / sqrtf(var + 1e-5f);
    float y[4];
#pragma unroll
    for(int u = 0; u < 4; ++u)
        y[u] = xc[u] * rs * ldin(g_, c0 + u, m) + ldin(b_, c0 + u, m);
    float4 st; st.x = y[0]; st.y = y[1]; st.z = y[2]; st.w = y[3];
    *(float4*)&xr[c0] = st;
    float cf = y[0]*ldin(cw_, c0+0, m) + y[1]*ldin(cw_, c0+1, m)
             + y[2]*ldin(cw_, c0+2, m) + y[3]*ldin(cw_, c0+3, m);
    float qq = y[0]*y[0] + y[1]*y[1] + y[2]*y[2] + y[3]*y[3];
    cf = wred_add(cf);
    qq = wred_add(qq);
    if((t & 63) == 0){ red2[t >> 6] = cf; red2[2 + (t >> 6)] = qq; }
    __syncthreads();
    if(t == 0){
        wgt[row] = expf(red2[0] + red2[1] + ldin(cb_, 0, m));
        x2a[row] = red2[2] + red2[3];
    }
}

// ---------- Gram staging + MAC ----------
#define GRAM2_CORE(AROWPTR, BROWPTR)                                               \
    for(int k0 = 0; k0 < 512; k0 += 16){                                           \
        int ia = t >> 1, kc = (t & 1) << 3;                                        \
        const float* ap = (AROWPTR) + k0 + kc;                                     \
        float4 a0 = *(const float4*)ap;                                            \
        float4 a1 = *(const float4*)(ap + 4);                                      \
        As[kc+0][ia] = a0.x; As[kc+1][ia] = a0.y; As[kc+2][ia] = a0.z; As[kc+3][ia] = a0.w; \
        As[kc+4][ia] = a1.x; As[kc+5][ia] = a1.y; As[kc+6][ia] = a1.z; As[kc+7][ia] = a1.w; \
        const float* bp = (BROWPTR) + k0 + kc;                                     \
        float4 b0 = *(const float4*)bp;                                            \
        float4 b1 = *(const float4*)(bp + 4);                                      \
        Bs[kc+0][ia] = b0.x; Bs[kc+1][ia] = b0.y; Bs[kc+2][ia] = b0.z; Bs[kc+3][ia] = b0.w; \
        Bs[kc+4][ia] = b1.x; Bs[kc+5][ia] = b1.y; Bs[kc+6][ia] = b1.z; Bs[kc+7][ia] = b1.w; \
        __syncthreads();                                                           \
        for(int kk = 0; kk < 16; ++kk){                                            \
            float4 a0r = *(const float4*)&As[kk][ty << 3];                         \
            float4 a1r = *(const float4*)&As[kk][(ty << 3) + 4];                   \
            float4 b0r = *(const float4*)&Bs[kk][tx << 2];                         \
            float4 b1r = *(const float4*)&Bs[kk][64 + (tx << 2)];                  \
            float ar[8] = {a0r.x, a0r.y, a0r.z, a0r.w, a1r.x, a1r.y, a1r.z, a1r.w};\
            float br[8] = {b0r.x, b0r.y, b0r.z, b0r.w, b1r.x, b1r.y, b1r.z, b1r.w};\
            for(int di = 0; di < 8; ++di)                                          \
                for(int dj = 0; dj < 8; ++dj)                                      \
                    acc[di][dj] = fmaf(ar[di], br[dj], acc[di][dj]);               \
        }                                                                          \
        __syncthreads();                                                           \
    }

// local j of slot u (u 0..7)
#define JLOC(u) (((u) < 4) ? ((tx << 2) + (u)) : (64 + (tx << 2) + (u) - 4))

// triangular block map: q -> (bi <= bj)
#define TRI_MAP(q, bi, bj)                                         \
    int bj = (int)((sqrtf(8.0f * (q) + 1.0f) - 1.0f) * 0.5f);      \
    while((bj + 1) * (bj + 2) / 2 <= (q)) bj++;                    \
    while(bj * (bj + 1) / 2 > (q)) bj--;                           \
    int bi = (q) - bj * (bj + 1) / 2;

// ---------- Pass A triangular, all batches (z = batch) ----------
__global__ __launch_bounds__(256) void gramA2(const float* Xb, const float* x2b,
                                              float* part5, float* pmax){
    __shared__ float As[16][132];
    __shared__ float Bs[16][132];
    __shared__ float colbuf[16][128];
    int z = blockIdx.z;
    TRI_MAP((int)blockIdx.x, bi, bj)
    int i0 = bi * 128, j0 = bj * 128;
    int t = threadIdx.x, tx = t & 15, ty = t >> 4;
    const float* X = Xb + (size_t)z * 2097152;
    float acc[8][8] = {};
    GRAM2_CORE(X + (size_t)(i0 + ia) * 512, X + (size_t)(j0 + ia) * 512)
    float xj[8];
#pragma unroll
    for(int u = 0; u < 8; ++u) xj[u] = x2b[(z << 12) + j0 + JLOC(u)];
    // row pass -> slot [i][bj]
#pragma unroll
    for(int di = 0; di < 8; ++di){
        int i = i0 + (ty << 3) + di;
        float xi = x2b[(z << 12) + i];
        float b5[5] = {FLTMAX, FLTMAX, FLTMAX, FLTMAX, FLTMAX};
        float mx = -FLTMAX;
#pragma unroll
        for(int u = 0; u < 8; ++u){
            float d2 = (xi + xj[u]) - 2.0f * acc[di][u];
            ins5(b5, d2);
            mx = fmaxf(mx, d2);
        }
        for(int mk = 1; mk < 16; mk <<= 1){
            float o0 = __shfl_xor(b5[0], mk), o1 = __shfl_xor(b5[1], mk),
                  o2 = __shfl_xor(b5[2], mk), o3 = __shfl_xor(b5[3], mk),
                  o4 = __shfl_xor(b5[4], mk);
            ins5(b5, o0); ins5(b5, o1); ins5(b5, o2); ins5(b5, o3); ins5(b5, o4);
            mx = fmaxf(mx, __shfl_xor(mx, mk));
        }
        if(tx == 0){
            size_t o = (((size_t)(z << 12) + i) * 32 + bj) * 5;
#pragma unroll
            for(int q = 0; q < 5; ++q) part5[o + q] = b5[q];
            pmax[((size_t)(z << 12) + i) * 32 + bj] = mx;
        }
    }
    // col pass (symmetry) -> slot [j][bi]; diagonal tiles skip (row pass covered slot)
    if(bi != bj){
        float xi8[8];
#pragma unroll
        for(int di = 0; di < 8; ++di) xi8[di] = x2b[(z << 12) + i0 + (ty << 3) + di];
        float c5[8][5];
        float cm[8];
#pragma unroll
        for(int u = 0; u < 8; ++u){
            c5[u][0] = FLTMAX; c5[u][1] = FLTMAX; c5[u][2] = FLTMAX;
            c5[u][3] = FLTMAX; c5[u][4] = FLTMAX;
            cm[u] = -FLTMAX;
#pragma unroll
            for(int di = 0; di < 8; ++di){
                float d2 = (xi8[di] + xj[u]) - 2.0f * acc[di][u];
                ins5(c5[u], d2);
                cm[u] = fmaxf(cm[u], d2);
            }
        }
        float m5[5] = {FLTMAX, FLTMAX, FLTMAX, FLTMAX, FLTMAX};
        float mm = -FLTMAX;
#pragma unroll
        for(int met = 0; met < 6; ++met){
            __syncthreads();
#pragma unroll
            for(int u = 0; u < 8; ++u)
                colbuf[ty][JLOC(u)] = (met < 5) ? c5[u][met] : cm[u];
            __syncthreads();
            if(t < 128){
                if(met < 5){
                    for(int r = 0; r < 16; ++r) ins5(m5, colbuf[r][t]);
                } else {
                    for(int r = 0; r < 16; ++r) mm = fmaxf(mm, colbuf[r][t]);
                }
            }
        }
        if(t < 128){
            size_t row = (size_t)(z << 12) + j0 + t;
            size_t o = (row * 32 + bi) * 5;
#pragma unroll
            for(int q = 0; q < 5; ++q) part5[o + q] = m5[q];
            pmax[row * 32 + bi] = mm;
        }
    }
}

__global__ __launch_bounds__(64) void reduceA2(const float* part5, const float* pmax,
                                               float* dens_b, int* dmax_b){
    int bi = blockIdx.x, t = threadIdx.x;     // bi = z*4096 + i, 0..16383
    __shared__ float l5[32][5];
    __shared__ float lm[32];
    if(t < 32){
#pragma unroll
        for(int q = 0; q < 5; ++q) l5[t][q] = part5[((size_t)bi * 32 + t) * 5 + q];
        lm[t] = pmax[(size_t)bi * 32 + t];
    }
    __syncthreads();
    if(t == 0){
        float m5[5] = {FLTMAX, FLTMAX, FLTMAX, FLTMAX, FLTMAX};
        float mm = -FLTMAX;
        for(int c = 0; c < 32; ++c){
            mm = fmaxf(mm, lm[c]);
#pragma unroll
            for(int q = 0; q < 5; ++q) ins5(m5, l5[c][q]);
        }
        const float sqrtC = 22.627416997969522f;
        float s = 0.f;
#pragma unroll
        for(int q = 0; q < 5; ++q){
            float d = sqrtf(fmaxf(m5[q], 0.f)) / sqrtC;
            s = s + d * d;
        }
        dens_b[bi] = expf(-(s / 5.0f));
        atomicMax(dmax_b + (bi >> 12), __float_as_int(fmaxf(mm, 0.f)));
    }
}

// ---------- Pass B triangular, all batches ----------
__global__ __launch_bounds__(256) void gramB2(const float* Xb, const float* x2b,
                                              const float* dens_b, float* pmin){
    __shared__ float As[16][132];
    __shared__ float Bs[16][132];
    __shared__ float colbuf[16][128];
    int z = blockIdx.z;
    TRI_MAP((int)blockIdx.x, bi, bj)
    int i0 = bi * 128, j0 = bj * 128;
    int t = threadIdx.x, tx = t & 15, ty = t >> 4;
    const float* X = Xb + (size_t)z * 2097152;
    float acc[8][8] = {};
    GRAM2_CORE(X + (size_t)(i0 + ia) * 512, X + (size_t)(j0 + ia) * 512)
    float xj[8], dj[8];
#pragma unroll
    for(int u = 0; u < 8; ++u){
        int j = j0 + JLOC(u);
        xj[u] = x2b[(z << 12) + j];
        dj[u] = dens_b[(z << 12) + j];
    }
    // row pass -> slot [i][bj]
#pragma unroll
    for(int di = 0; di < 8; ++di){
        int i = i0 + (ty << 3) + di;
        float xi = x2b[(z << 12) + i];
        float deni = dens_b[(z << 12) + i];
        float pm = FLTMAX;
#pragma unroll
        for(int u = 0; u < 8; ++u){
            if(dj[u] > deni){
                float d2 = (xi + xj[u]) - 2.0f * acc[di][u];
                pm = fminf(pm, d2);
            }
        }
        for(int mk = 1; mk < 16; mk <<= 1)
            pm = fminf(pm, __shfl_xor(pm, mk));
        if(tx == 0) pmin[((size_t)(z << 12) + i) * 32 + bj] = pm;
    }
    // col pass (symmetry) -> slot [j][bi]
    if(bi != bj){
        float xi8[8], di8[8];
#pragma unroll
        for(int di = 0; di < 8; ++di){
            int i = i0 + (ty << 3) + di;
            xi8[di] = x2b[(z << 12) + i];
            di8[di] = dens_b[(z << 12) + i];
        }
        __syncthreads();
#pragma unroll
        for(int u = 0; u < 8; ++u){
            float denj = dj[u];
            float pm = FLTMAX;
#pragma unroll
            for(int di = 0; di < 8; ++di){
                if(di8[di] > denj){
                    float d2 = (xi8[di] + xj[u]) - 2.0f * acc[di][u];
                    pm = fminf(pm, d2);
                }
            }
            colbuf[ty][JLOC(u)] = pm;
        }
        __syncthreads();
        if(t < 128){
            float m = FLTMAX;
            for(int r = 0; r < 16; ++r) m = fminf(m, colbuf[r][t]);
            pmin[((size_t)(z << 12) + j0 + t) * 32 + bi] = m;
        }
    }
}

__global__ __launch_bounds__(64) void reduceB2(const float* pmin, const float* dens_b,
                                               const int* dmax_b, float* score_b){
    int bi = blockIdx.x, t = threadIdx.x;     // 0..16383
    __shared__ float lm[32];
    if(t < 32) lm[t] = pmin[(size_t)bi * 32 + t];
    __syncthreads();
    if(t == 0){
        float m = FLTMAX;
        for(int c = 0; c < 32; ++c) m = fminf(m, lm[c]);
        const float sqrtC = 22.627416997969522f;
        float dp;
        if(m == FLTMAX) dp = sqrtf(fmaxf(__int_as_float(dmax_b[bi >> 12]), 0.f)) / sqrtC;
        else            dp = sqrtf(fmaxf(m, 0.f)) / sqrtC;
        score_b[bi] = dp * dens_b[bi];
    }
}

// ---------- Pass C: gathered-center Gram -> per-(token, centerblock) argmin ----------
__global__ __launch_bounds__(256) void gramC2(const float* Xb, const float* x2b,
                                              const int* idown_b, float* pcd, int* pci){
    __shared__ float As[16][132];
    __shared__ float Bs[16][132];
    __shared__ float ldd[16][128];
    __shared__ int   ldi[16][128];
    int z = blockIdx.z;
    int s0 = blockIdx.y * 128, j0 = blockIdx.x * 128;
    int t = threadIdx.x, tx = t & 15, ty = t >> 4;
    const float* X = Xb + (size_t)z * 2097152;
    const int* idz = idown_b + (z << 10);
    float acc[8][8] = {};
    GRAM2_CORE(X + (size_t)idz[s0 + ia] * 512, X + (size_t)(j0 + ia) * 512)
    const float sqrtC = 22.627416997969522f;
    float xc[8];
#pragma unroll
    for(int di = 0; di < 8; ++di) xc[di] = x2b[(z << 12) + idz[s0 + (ty << 3) + di]];
#pragma unroll
    for(int u = 0; u < 8; ++u){
        int jl = JLOC(u);
        float xj = x2b[(z << 12) + j0 + jl];
        float bd = FLTMAX;
        int bs = 0;
#pragma unroll
        for(int di = 0; di < 8; ++di){           // di ascending => first-min ties stay first
            float d2 = (xc[di] + xj) - 2.0f * acc[di][u];
            float d = sqrtf(fmaxf(d2, 0.f)) / sqrtC;
            if(d < bd){ bd = d; bs = s0 + (ty << 3) + di; }
        }
        ldd[ty][jl] = bd;
        ldi[ty][jl] = bs;
    }
    __syncthreads();
    if(t < 128){
        float bd = FLTMAX;
        int bs = 0;
        for(int r = 0; r < 16; ++r){              // r ascending => center index ascending
            float d = ldd[r][t];
            if(d < bd){ bd = d; bs = ldi[r][t]; }
        }
        pcd[((size_t)(z << 12) + j0 + t) * 8 + blockIdx.y] = bd;
        pci[((size_t)(z << 12) + j0 + t) * 8 + blockIdx.y] = bs;
    }
}

__global__ void reduceC2(const float* pcd, const int* pci, int* iclus_b){
    int jg = blockIdx.x * 256 + threadIdx.x;      // 0..16383
    float bd = FLTMAX;
    int bs = 0;
    for(int c = 0; c < 8; ++c){
        float d = pcd[(size_t)jg * 8 + c];
        if(d < bd){ bd = d; bs = pci[(size_t)jg * 8 + c]; }
    }
    iclus_b[jg] = bs;
}

// ---------- bitonic sort (score desc, idx asc) -> top 1024; blockIdx.x = batch ----------
__global__ __launch_bounds__(1024) void sort_topk(const float* score, int* idown){
    __shared__ float ss[4096];
    __shared__ int sid[4096];
    int t = threadIdx.x;
    const float* sc = score + (size_t)blockIdx.x * 4096;
    int* id = idown + (size_t)blockIdx.x * 1024;
    for(int v = t; v < 4096; v += 1024){ ss[v] = sc[v]; sid[v] = v; }
    __syncthreads();
    for(int k = 2; k <= 4096; k <<= 1){
        for(int j = k >> 1; j > 0; j >>= 1){
            for(int v = t; v < 4096; v += 1024){
                int l = v ^ j;
                if(l > v){
                    float sv = ss[v], sl = ss[l];
                    int iv = sid[v], il = sid[l];
                    bool before_lv = (sl > sv) || (sl == sv && il < iv);
                    bool before_vl = (sv > sl) || (sv == sl && iv < il);
                    bool asc = ((v & k) == 0);
                    bool sw = asc ? before_lv : before_vl;
                    if(sw){ ss[v] = sl; ss[l] = sv; sid[v] = il; sid[l] = iv; }
                }
            }
            __syncthreads();
        }
    }
    for(int v = t; v < 1024; v += 1024) id[v] = sid[v];
}

// ---------- merge tokens + outputs (FLOAT32 out) ----------
__global__ void allw_add(const int* iclus, const float* wgt, float* allw){
    int e = blockIdx.x * 256 + threadIdx.x;   // 16384
    int b = e >> 12;
    unsafeAtomicAdd(&allw[(b << 10) + (iclus[e] & 1023)], wgt[e]);
}
__global__ void norm_k(const int* iclus, const float* wgt, const float* allw, float* nw){
    int e = blockIdx.x * 256 + threadIdx.x;
    int b = e >> 12;
    nw[e] = wgt[e] / allw[(b << 10) + (iclus[e] & 1023)];
}
__global__ void abuf_k(const int* idx_agg, const void* aggw, const float* nw,
                       float* abuf, float* maxw, const int* mode){
    int m = *mode;
    int e = blockIdx.x * 256 + threadIdx.x;
    int b = e >> 12;
    float a = ldin(aggw, e, m) * nw[(b << 12) + (idx_agg[e] & 4095)];
    abuf[e] = a;
    atomicMax((int*)&maxw[b], __float_as_int(a));
}
__global__ __launch_bounds__(128) void scatter_xdown(const int* iclus, const float* nw,
                                                     const float* xtok, float* xdown){
    int bn = blockIdx.x;           // 0..16383
    int b = bn >> 12;
    int cl = iclus[bn] & 1023;
    float w = nw[bn];
    const float* src = xtok + (size_t)bn * 512;
    float* dst = xdown + ((size_t)(b << 10) + cl) * 512;
    int c = threadIdx.x * 4;
    float4 v = *(const float4*)&src[c];
    unsafeAtomicAdd(&dst[c + 0], v.x * w);
    unsafeAtomicAdd(&dst[c + 1], v.y * w);
    unsafeAtomicAdd(&dst[c + 2], v.z * w);
    unsafeAtomicAdd(&dst[c + 3], v.w * w);
}

__global__ void out0_k(const float* xdown, float* out){
    int e = blockIdx.x * 256 + threadIdx.x;
    if(e < 2097152) out[e] = xdown[e];
}
__global__ void out1_k(const int* idx_agg, const int* iclus, float* out){
    int e = blockIdx.x * 256 + threadIdx.x;   // 16384
    int b = e >> 12;
    int ic = iclus[(b << 12) + (idx_agg[e] & 4095)];
    out[e] = (float)ic;
}
__global__ void out2_k(const float* abuf, const float* maxw, float* out){
    int e = blockIdx.x * 256 + threadIdx.x;
    int b = e >> 12;
    out[e] = abuf[e] / maxw[b];
}

// ---------- launch ----------
extern "C" void kernel_launch(void* const* d_in, const int* in_sizes, int n_in,
                              void* d_out, int out_size, void* d_ws, size_t ws_size,
                              hipStream_t stream){
    (void)in_sizes; (void)n_in; (void)out_size; (void)ws_size;
    const void* x    = d_in[0];
    const void* loc  = d_in[1];
    const int* idx_agg = (const int*)d_in[2];
    const void* aggw = d_in[3];
    const void* cw   = d_in[7];
    const void* cb   = d_in[8];
    const void* sw   = d_in[9];
    const void* lg   = d_in[10];
    const void* lnb  = d_in[11];
    const void* cfw  = d_in[12];
    const void* cfb  = d_in[13];
    float* out = (float*)d_out;

    // Flat alias-free layout: 20,848,649 floats = 83.4 MB.
    // ws >= 101,154,852 B proven (round-7 profile shows the fast-path kernel executed).
    float* ws    = (float*)d_ws;
    float* xtok  = ws;                      // 8,388,608
    float* xmap  = ws + 8388608;            // 4,194,304
    float* cnt   = ws + 12582912;           // 16,384
    float* convo = ws + 12599296;           // 2,097,152
    float* part5 = ws + 14696448;           // 16384*32*5 = 2,621,440
    float* pmaxb = ws + 17317888;           // 524,288
    float* pminb = ws + 17842176;           // 524,288
    float* pcd   = ws + 18366464;           // 131,072
    int*   pci   = (int*)(ws + 18497536);   // 131,072
    float* xdown = ws + 18628608;           // 2,097,152
    float* x2    = ws + 20725760;           // 16,384
    float* wgt   = ws + 20742144;           // 16,384
    float* dens  = ws + 20758528;           // 16,384
    float* score = ws + 20774912;           // 16,384
    float* wsum  = ws + 20791296;           // 16,384
    float* allw  = ws + 20807680;           // 4,096
    float* nw    = ws + 20811776;           // 16,384
    float* dmaxf = ws + 20828160;           // 4
    float* maxw  = ws + 20828164;           // 4
    int*   idown = (int*)(ws + 20828168);   // 4,096
    int*   iclus = (int*)(ws + 20832264);   // 16,384
    int*   mode  = (int*)(ws + 20848648);   // 1

    detect_mode<<<1, 256, 0, stream>>>(x, mode);

    hipMemsetAsync(xmap, 0, (size_t)4194304 * 4, stream);
    hipMemsetAsync(cnt, 0, (size_t)16384 * 4, stream);
    hipMemsetAsync(dmaxf, 0, 8 * 4, stream);            // dmax[4] + maxw[4] adjacent
    hipMemsetAsync(xdown, 0, (size_t)2097152 * 4, stream);
    fill_f32<<<64, 256, 0, stream>>>(wsum, 1e-6f, 16384);
    fill_f32<<<16, 256, 0, stream>>>(allw, 1e-6f, 4096);

    scatter_map<<<16384, 256, 0, stream>>>(x, loc, idx_agg, xmap, cnt, mode);
    divide_map<<<16384, 256, 0, stream>>>(xmap, cnt, 4194304);

    init_convo<<<8192, 256, 0, stream>>>(convo, cb, mode);
    gemm_conv<<<dim3(4, 32, 8), 256, 0, stream>>>(xmap, cw, convo, mode);
    gemm_skip<<<dim3(8, 256), 256, 0, stream>>>(x, sw, xtok, mode);

    wsum_add<<<64, 256, 0, stream>>>(idx_agg, aggw, wsum, mode);
    scatter_tok<<<16384, 128, 0, stream>>>(loc, idx_agg, aggw, convo, wsum, xtok, mode);
    ln_conf<<<16384, 128, 0, stream>>>(xtok, lg, lnb, cfw, cfb, wgt, x2, mode);

    // ---- clustering: all 4 batches in one 7-launch chain ----
    gramA2<<<dim3(528, 1, 4), 256, 0, stream>>>(xtok, x2, part5, pmaxb);
    reduceA2<<<16384, 64, 0, stream>>>(part5, pmaxb, dens, (int*)dmaxf);
    gramB2<<<dim3(528, 1, 4), 256, 0, stream>>>(xtok, x2, dens, pminb);
    reduceB2<<<16384, 64, 0, stream>>>(pminb, dens, (int*)dmaxf, score);
    sort_topk<<<4, 1024, 0, stream>>>(score, idown);
    gramC2<<<dim3(32, 8, 4), 256, 0, stream>>>(xtok, x2, idown, pcd, pci);
    reduceC2<<<64, 256, 0, stream>>>(pcd, pci, iclus);

    allw_add<<<64, 256, 0, stream>>>(iclus, wgt, allw);
    norm_k<<<64, 256, 0, stream>>>(iclus, wgt, allw, nw);
    abuf_k<<<64, 256, 0, stream>>>(idx_agg, aggw, nw, score, maxw, mode);   // score reused as abuf

    scatter_xdown<<<16384, 128, 0, stream>>>(iclus, nw, xtok, xdown);

    out0_k<<<8192, 256, 0, stream>>>(xdown, out);
    out1_k<<<64, 256, 0, stream>>>(idx_agg, iclus, out + 2097152);
    out2_k<<<64, 256, 0, stream>>>(score, maxw, out + 2097152 + 16384);
}

// Round 9
// 2398.908 us; speedup vs baseline: 1.1863x; 1.0144x over previous
//
#include <hip/hip_runtime.h>

#define FLTMAX 3.402823466e+38f

// ---------- helpers ----------
__device__ inline float b2f(unsigned short u){
    return __uint_as_float(((unsigned int)u) << 16);
}
// flag-dispatched input load: mode=1 -> f32 buffer, mode=0 -> bf16 buffer
__device__ inline float ldin(const void* p, long i, int f32m){
    return f32m ? ((const float*)p)[i] : b2f(((const unsigned short*)p)[i]);
}
__device__ inline int pix_idx(float lx, float ly, float half, int wh){
    lx = fminf(fmaxf(lx, -1.f), 1.f);
    ly = fminf(fmaxf(ly, -1.f), 1.f);
    int px = (int)rintf((lx + 1.f) * half - 0.5f);   // round-half-even = jnp.round
    int py = (int)rintf((ly + 1.f) * half - 0.5f);
    px = min(max(px, 0), wh - 1);
    py = min(max(py, 0), wh - 1);
    return py * wh + px;
}
__device__ inline void ins5(float* b5, float d){
    if(d < b5[4]){
        b5[4] = d;
#pragma unroll
        for(int q = 4; q > 0; --q){
            if(b5[q] < b5[q-1]){ float tm = b5[q]; b5[q] = b5[q-1]; b5[q-1] = tm; }
        }
    }
}
__device__ inline float wred_add(float v){
    for(int o = 32; o > 0; o >>= 1) v += __shfl_down(v, o);
    return v;
}

// ---------- dtype auto-detect ----------
__global__ __launch_bounds__(256) void detect_mode(const void* xraw, int* flag){
    __shared__ int sh[256];
    const unsigned short* p = (const unsigned short*)xraw;
    int t = threadIdx.x, c = 0;
    for(int i = t; i < 65536; i += 256){
        float v = b2f(p[i]);
        if(!(fabsf(v) < 100.f)) c++;
    }
    sh[t] = c;
    __syncthreads();
    for(int s = 128; s > 0; s >>= 1){
        if(t < s) sh[t] += sh[t + s];
        __syncthreads();
    }
    if(t == 0) flag[0] = (sh[0] > 64) ? 1 : 0;
}

// ---------- small utility kernels ----------
__global__ void fill_f32(float* p, float v, int n){
    int i = blockIdx.x * blockDim.x + threadIdx.x;
    if(i < n) p[i] = v;
}

// token2map scatter
__global__ __launch_bounds__(256) void scatter_map(const void* x, const void* loc,
                                                   const int* idx_agg, float* acc, float* cnt,
                                                   const int* mode){
    int m = *mode;
    int bn = blockIdx.x;                 // 0..16383
    int b = bn >> 12;
    float lx = ldin(loc, (long)bn * 2 + 0, m);
    float ly = ldin(loc, (long)bn * 2 + 1, m);
    int p = pix_idx(lx, ly, 32.f, 64);
    int ia = idx_agg[bn] & 4095;
    long src = ((long)(b << 12) + ia) * 256;
    float* dst = acc + ((size_t)(b << 12) + p) * 256;
    int t = threadIdx.x;                 // 256 = C
    unsafeAtomicAdd(&dst[t], ldin(x, src + t, m));
    if(t == 0) unsafeAtomicAdd(&cnt[(b << 12) + p], 1.0f);
}

__global__ void divide_map(float* xmap, const float* cnt, int n){
    int i = blockIdx.x * 256 + threadIdx.x;
    if(i < n) xmap[i] = xmap[i] / (cnt[i >> 8] + 1e-6f);
}

// ---------- GEMM: skip  (x[16384,256] @ skip_w[256,512] -> xtok f32) ----------
__global__ __launch_bounds__(256) void gemm_skip(const void* A, const void* Bw, float* C,
                                                 const int* mode){
    int m = *mode;
    __shared__ float As[16][68];
    __shared__ float Bs[16][68];
    int i0 = blockIdx.y * 64, j0 = blockIdx.x * 64;
    int t = threadIdx.x, tx = t & 15, ty = t >> 4;
    float acc[4][4] = {};
    for(int k0 = 0; k0 < 256; k0 += 16){
        int ia = t >> 2, kc = (t & 3) << 2;
#pragma unroll
        for(int u = 0; u < 4; ++u)
            As[kc+u][ia] = ldin(A, (long)(i0 + ia) * 256 + k0 + kc + u, m);
        int kb = t >> 4, jb = (t & 15) << 2;
        float4 bv;
        bv.x = ldin(Bw, (long)(k0 + kb) * 512 + j0 + jb + 0, m);
        bv.y = ldin(Bw, (long)(k0 + kb) * 512 + j0 + jb + 1, m);
        bv.z = ldin(Bw, (long)(k0 + kb) * 512 + j0 + jb + 2, m);
        bv.w = ldin(Bw, (long)(k0 + kb) * 512 + j0 + jb + 3, m);
        *(float4*)&Bs[kb][jb] = bv;
        __syncthreads();
#pragma unroll
        for(int kk = 0; kk < 16; ++kk){
            float4 a4 = *(const float4*)&As[kk][ty << 2];
            float4 b4 = *(const float4*)&Bs[kk][tx << 2];
            float ar[4] = {a4.x, a4.y, a4.z, a4.w};
            float br[4] = {b4.x, b4.y, b4.z, b4.w};
#pragma unroll
            for(int di = 0; di < 4; ++di)
#pragma unroll
                for(int dj = 0; dj < 4; ++dj)
                    acc[di][dj] = fmaf(ar[di], br[dj], acc[di][dj]);
        }
        __syncthreads();
    }
#pragma unroll
    for(int di = 0; di < 4; ++di){
        size_t i = i0 + (ty << 2) + di;
#pragma unroll
        for(int dj = 0; dj < 4; ++dj)
            C[i * 512 + j0 + (tx << 2) + dj] = acc[di][dj];
    }
}

// ---------- conv C init with bias ----------
__global__ void init_convo(float* convo, const void* bias, const int* mode){
    int m = *mode;
    int e = blockIdx.x * 256 + threadIdx.x;   // 2,097,152
    convo[e] = ldin(bias, e & 511, m);
}

// ---------- conv3x3 s2 p1 via im2col: 128x128 tile, K-split x8, prefetch, atomic epilogue ----------
__global__ __launch_bounds__(256) void gemm_conv(const float* xmap, const void* Bw,
                                                 float* C, const int* mode){
    int m = *mode;
    __shared__ float As[16][132];
    __shared__ float Bs[16][132];
    int i0 = blockIdx.y * 128, j0 = blockIdx.x * 128;
    int kz = blockIdx.z;                       // 0..7, K chunk of 288
    int t = threadIdx.x, tx = t & 15, ty = t >> 4;
    int ia = t >> 1, kc = (t & 1) << 3;        // it-invariant
    int p = i0 + ia;
    int b = p >> 10, r = p & 1023, oy = r >> 5, ox = r & 31;
    int kb = t >> 4, jb = (t & 15) << 3;
    float acc[8][8] = {};
    float4 v0, v1, w0, w1;
    // load it=0
    {
        int k0 = kz * 288;
        int f = k0 >> 8; int ky = f / 3, kx = f % 3; int c0 = k0 & 255;
        int iy = 2 * oy - 1 + ky, ix = 2 * ox - 1 + kx;
        v0 = make_float4(0.f,0.f,0.f,0.f); v1 = v0;
        if(iy >= 0 && iy < 64 && ix >= 0 && ix < 64){
            const float* src = &xmap[((size_t)(b << 12) + (iy << 6) + ix) * 256 + c0 + kc];
            v0 = *(const float4*)src; v1 = *(const float4*)(src + 4);
        }
        long bo = (long)(k0 + kb) * 512 + j0 + jb;
        w0.x = ldin(Bw, bo+0, m); w0.y = ldin(Bw, bo+1, m);
        w0.z = ldin(Bw, bo+2, m); w0.w = ldin(Bw, bo+3, m);
        w1.x = ldin(Bw, bo+4, m); w1.y = ldin(Bw, bo+5, m);
        w1.z = ldin(Bw, bo+6, m); w1.w = ldin(Bw, bo+7, m);
    }
    for(int it = 0; it < 18; ++it){
        As[kc+0][ia] = v0.x; As[kc+1][ia] = v0.y; As[kc+2][ia] = v0.z; As[kc+3][ia] = v0.w;
        As[kc+4][ia] = v1.x; As[kc+5][ia] = v1.y; As[kc+6][ia] = v1.z; As[kc+7][ia] = v1.w;
        *(float4*)&Bs[kb][jb] = w0;
        *(float4*)&Bs[kb][jb+4] = w1;
        if(it + 1 < 18){                      // prefetch it+1 before the barrier
            int k0 = kz * 288 + (it + 1) * 16;
            int f = k0 >> 8; int ky = f / 3, kx = f % 3; int c0 = k0 & 255;
            int iy = 2 * oy - 1 + ky, ix = 2 * ox - 1 + kx;
            v0 = make_float4(0.f,0.f,0.f,0.f); v1 = v0;
            if(iy >= 0 && iy < 64 && ix >= 0 && ix < 64){
                const float* src = &xmap[((size_t)(b << 12) + (iy << 6) + ix) * 256 + c0 + kc];
                v0 = *(const float4*)src; v1 = *(const float4*)(src + 4);
            }
            long bo = (long)(k0 + kb) * 512 + j0 + jb;
            w0.x = ldin(Bw, bo+0, m); w0.y = ldin(Bw, bo+1, m);
            w0.z = ldin(Bw, bo+2, m); w0.w = ldin(Bw, bo+3, m);
            w1.x = ldin(Bw, bo+4, m); w1.y = ldin(Bw, bo+5, m);
            w1.z = ldin(Bw, bo+6, m); w1.w = ldin(Bw, bo+7, m);
        }
        __syncthreads();
#pragma unroll
        for(int kk = 0; kk < 16; ++kk){
            float4 a0r = *(const float4*)&As[kk][ty << 3];
            float4 a1r = *(const float4*)&As[kk][(ty << 3) + 4];
            float4 b0r = *(const float4*)&Bs[kk][tx << 2];
            float4 b1r = *(const float4*)&Bs[kk][64 + (tx << 2)];
            float ar[8] = {a0r.x, a0r.y, a0r.z, a0r.w, a1r.x, a1r.y, a1r.z, a1r.w};
            float br[8] = {b0r.x, b0r.y, b0r.z, b0r.w, b1r.x, b1r.y, b1r.z, b1r.w};
#pragma unroll
            for(int di = 0; di < 8; ++di)
#pragma unroll
                for(int dj = 0; dj < 8; ++dj)
                    acc[di][dj] = fmaf(ar[di], br[dj], acc[di][dj]);
        }
        __syncthreads();
    }
#pragma unroll
    for(int di = 0; di < 8; ++di){
        size_t i = i0 + (ty << 3) + di;
#pragma unroll
        for(int u = 0; u < 4; ++u){
            unsafeAtomicAdd(&C[i * 512 + j0 + (tx << 2) + u], acc[di][u]);
            unsafeAtomicAdd(&C[i * 512 + j0 + 64 + (tx << 2) + u], acc[di][4 + u]);
        }
    }
}

// ---------- map2token ----------
__global__ void wsum_add(const int* idx_agg, const void* aggw, float* wsum, const int* mode){
    int m = *mode;
    int e = blockIdx.x * 256 + threadIdx.x;   // 16384
    int b = e >> 12;
    unsafeAtomicAdd(&wsum[(b << 12) + (idx_agg[e] & 4095)], ldin(aggw, e, m));
}

__global__ __launch_bounds__(128) void scatter_tok(const void* loc, const int* idx_agg,
                                                   const void* aggw, const float* convo,
                                                   const float* wsum, float* xtok, const int* mode){
    int m = *mode;
    int bn = blockIdx.x;
    int b = bn >> 12;
    float lx = ldin(loc, (long)bn * 2 + 0, m);
    float ly = ldin(loc, (long)bn * 2 + 1, m);
    int p = pix_idx(lx, ly, 16.f, 32);
    int tk = idx_agg[bn] & 4095;
    float w = ldin(aggw, bn, m);
    float scale = w / wsum[(b << 12) + tk];
    const float* pv = convo + ((size_t)(b << 10) + p) * 512;
    float* dst = xtok + ((size_t)(b << 12) + tk) * 512;
    int c = threadIdx.x * 4;
    float4 v = *(const float4*)&pv[c];
    unsafeAtomicAdd(&dst[c + 0], v.x * scale);
    unsafeAtomicAdd(&dst[c + 1], v.y * scale);
    unsafeAtomicAdd(&dst[c + 2], v.z * scale);
    unsafeAtomicAdd(&dst[c + 3], v.w * scale);
}

// ---------- fused layernorm + conf + weight + x2 ----------
__global__ __launch_bounds__(128) void ln_conf(float* xtok, const void* g_, const void* b_,
                                               const void* cw_, const void* cb_,
                                               float* wgt, float* x2a, const int* mode){
    int m = *mode;
    int row = blockIdx.x;        // 0..16383
    int t = threadIdx.x;         // 128
    float* xr = xtok + (size_t)row * 512;
    int c0 = t * 4;
    float4 v = *(const float4*)&xr[c0];
    float xv[4] = {v.x, v.y, v.z, v.w};
    __shared__ float red[2];
    __shared__ float red2[4];
    float s = xv[0] + xv[1] + xv[2] + xv[3];
    s = wred_add(s);
    if((t & 63) == 0) red[t >> 6] = s;
    __syncthreads();
    float mean = (red[0] + red[1]) * (1.f / 512.f);
    __syncthreads();
    float xc[4];
#pragma unroll
    for(int u = 0; u < 4; ++u) xc[u] = xv[u] - mean;
    float q = xc[0]*xc[0] + xc[1]*xc[1] + xc[2]*xc[2] + xc[3]*xc[3];
    q = wred_add(q);
    if((t & 63) == 0) red[t >> 6] = q;
    __syncthreads();
    float var = (red[0] + red[1]) * (1.f / 512.f);
    float rs = 1.0f / sqrtf(var + 1e-5f);
    float y[4];
#pragma unroll
    for(int u = 0; u < 4; ++u)
        y[u] = xc[u] * rs * ldin(g_, c0 + u, m) + ldin(b_, c0 + u, m);
    float4 st; st.x = y[0]; st.y = y[1]; st.z = y[2]; st.w = y[3];
    *(float4*)&xr[c0] = st;
    float cf = y[0]*ldin(cw_, c0+0, m) + y[1]*ldin(cw_, c0+1, m)
             + y[2]*ldin(cw_, c0+2, m) + y[3]*ldin(cw_, c0+3, m);
    float qq = y[0]*y[0] + y[1]*y[1] + y[2]*y[2] + y[3]*y[3];
    cf = wred_add(cf);
    qq = wred_add(qq);
    if((t & 63) == 0){ red2[t >> 6] = cf; red2[2 + (t >> 6)] = qq; }
    __syncthreads();
    if(t == 0){
        wgt[row] = expf(red2[0] + red2[1] + ldin(cb_, 0, m));
        x2a[row] = red2[2] + red2[3];
    }
}

// ---------- Gram staging + MAC with register prefetch (bit-identical arithmetic) ----------
#define GRAM2_CORE(AROWPTR, BROWPTR)                                               \
    {                                                                              \
    int ia = t >> 1, kc = (t & 1) << 3;                                            \
    const float* Ap = (AROWPTR) + kc;                                              \
    const float* Bp = (BROWPTR) + kc;                                              \
    float4 na0 = *(const float4*)Ap;                                               \
    float4 na1 = *(const float4*)(Ap + 4);                                         \
    float4 nb0 = *(const float4*)Bp;                                               \
    float4 nb1 = *(const float4*)(Bp + 4);                                         \
    for(int k0 = 0; k0 < 512; k0 += 16){                                           \
        float4 a0 = na0, a1 = na1, b0 = nb0, b1 = nb1;                             \
        As[kc+0][ia] = a0.x; As[kc+1][ia] = a0.y; As[kc+2][ia] = a0.z; As[kc+3][ia] = a0.w; \
        As[kc+4][ia] = a1.x; As[kc+5][ia] = a1.y; As[kc+6][ia] = a1.z; As[kc+7][ia] = a1.w; \
        Bs[kc+0][ia] = b0.x; Bs[kc+1][ia] = b0.y; Bs[kc+2][ia] = b0.z; Bs[kc+3][ia] = b0.w; \
        Bs[kc+4][ia] = b1.x; Bs[kc+5][ia] = b1.y; Bs[kc+6][ia] = b1.z; Bs[kc+7][ia] = b1.w; \
        if(k0 + 16 < 512){                                                         \
            na0 = *(const float4*)(Ap + k0 + 16);                                  \
            na1 = *(const float4*)(Ap + k0 + 20);                                  \
            nb0 = *(const float4*)(Bp + k0 + 16);                                  \
            nb1 = *(const float4*)(Bp + k0 + 20);                                  \
        }                                                                          \
        __syncthreads();                                                           \
        for(int kk = 0; kk < 16; ++kk){                                            \
            float4 a0r = *(const float4*)&As[kk][ty << 3];                         \
            float4 a1r = *(const float4*)&As[kk][(ty << 3) + 4];                   \
            float4 b0r = *(const float4*)&Bs[kk][tx << 2];                         \
            float4 b1r = *(const float4*)&Bs[kk][64 + (tx << 2)];                  \
            float ar[8] = {a0r.x, a0r.y, a0r.z, a0r.w, a1r.x, a1r.y, a1r.z, a1r.w};\
            float br[8] = {b0r.x, b0r.y, b0r.z, b0r.w, b1r.x, b1r.y, b1r.z, b1r.w};\
            for(int di = 0; di < 8; ++di)                                          \
                for(int dj = 0; dj < 8; ++dj)                                      \
                    acc[di][dj] = fmaf(ar[di], br[dj], acc[di][dj]);               \
        }                                                                          \
        __syncthreads();                                                           \
    }                                                                              \
    }

// local j of slot u (u 0..7)
#define JLOC(u) (((u) < 4) ? ((tx << 2) + (u)) : (64 + (tx << 2) + (u) - 4))

// triangular block map: q -> (bi <= bj)
#define TRI_MAP(q, bi, bj)                                         \
    int bj = (int)((sqrtf(8.0f * (q) + 1.0f) - 1.0f) * 0.5f);      \
    while((bj + 1) * (bj + 2) / 2 <= (q)) bj++;                    \
    while(bj * (bj + 1) / 2 > (q)) bj--;                           \
    int bi = (q) - bj * (bj + 1) / 2;

// ---------- Pass A triangular, all batches (z = batch) ----------
__global__ __launch_bounds__(256) void gramA2(const float* Xb, const float* x2b,
                                              float* part5, float* pmax){
    __shared__ float As[16][132];
    __shared__ float Bs[16][132];
    __shared__ float colbuf[16][129];     // 129: bank = (ty+jl)%32 -> 2-way (free)
    int z = blockIdx.z;
    TRI_MAP((int)blockIdx.x, bi, bj)
    int i0 = bi * 128, j0 = bj * 128;
    int t = threadIdx.x, tx = t & 15, ty = t >> 4;
    const float* X = Xb + (size_t)z * 2097152;
    float acc[8][8] = {};
    GRAM2_CORE(X + (size_t)(i0 + ia) * 512, X + (size_t)(j0 + ia) * 512)
    float xj[8];
#pragma unroll
    for(int u = 0; u < 8; ++u) xj[u] = x2b[(z << 12) + j0 + JLOC(u)];
    // row pass -> slot [i][bj]
#pragma unroll
    for(int di = 0; di < 8; ++di){
        int i = i0 + (ty << 3) + di;
        float xi = x2b[(z << 12) + i];
        float b5[5] = {FLTMAX, FLTMAX, FLTMAX, FLTMAX, FLTMAX};
        float mx = -FLTMAX;
#pragma unroll
        for(int u = 0; u < 8; ++u){
            float d2 = (xi + xj[u]) - 2.0f * acc[di][u];
            ins5(b5, d2);
            mx = fmaxf(mx, d2);
        }
        for(int mk = 1; mk < 16; mk <<= 1){
            float o0 = __shfl_xor(b5[0], mk), o1 = __shfl_xor(b5[1], mk),
                  o2 = __shfl_xor(b5[2], mk), o3 = __shfl_xor(b5[3], mk),
                  o4 = __shfl_xor(b5[4], mk);
            ins5(b5, o0); ins5(b5, o1); ins5(b5, o2); ins5(b5, o3); ins5(b5, o4);
            mx = fmaxf(mx, __shfl_xor(mx, mk));
        }
        if(tx == 0){
            size_t o = (((size_t)(z << 12) + i) * 32 + bj) * 5;
#pragma unroll
            for(int q = 0; q < 5; ++q) part5[o + q] = b5[q];
            pmax[((size_t)(z << 12) + i) * 32 + bj] = mx;
        }
    }
    // col pass (symmetry) -> slot [j][bi]; diagonal tiles skip (row pass covered slot)
    if(bi != bj){
        float xi8[8];
#pragma unroll
        for(int di = 0; di < 8; ++di) xi8[di] = x2b[(z << 12) + i0 + (ty << 3) + di];
        float c5[8][5];
        float cm[8];
#pragma unroll
        for(int u = 0; u < 8; ++u){
            c5[u][0] = FLTMAX; c5[u][1] = FLTMAX; c5[u][2] = FLTMAX;
            c5[u][3] = FLTMAX; c5[u][4] = FLTMAX;
            cm[u] = -FLTMAX;
#pragma unroll
            for(int di = 0; di < 8; ++di){
                float d2 = (xi8[di] + xj[u]) - 2.0f * acc[di][u];
                ins5(c5[u], d2);
                cm[u] = fmaxf(cm[u], d2);
            }
        }
        float m5[5] = {FLTMAX, FLTMAX, FLTMAX, FLTMAX, FLTMAX};
        float mm = -FLTMAX;
#pragma unroll
        for(int met = 0; met < 6; ++met){
            __syncthreads();
#pragma unroll
            for(int u = 0; u < 8; ++u)
                colbuf[ty][JLOC(u)] = (met < 5) ? c5[u][met] : cm[u];
            __syncthreads();
            if(t < 128){
                if(met < 5){
                    for(int r = 0; r < 16; ++r) ins5(m5, colbuf[r][t]);
                } else {
                    for(int r = 0; r < 16; ++r) mm = fmaxf(mm, colbuf[r][t]);
                }
            }
        }
        if(t < 128){
            size_t row = (size_t)(z << 12) + j0 + t;
            size_t o = (row * 32 + bi) * 5;
#pragma unroll
            for(int q = 0; q < 5; ++q) part5[o + q] = m5[q];
            pmax[row * 32 + bi] = mm;
        }
    }
}

__global__ __launch_bounds__(64) void reduceA2(const float* part5, const float* pmax,
                                               float* dens_b, int* dmax_b){
    int bi = blockIdx.x, t = threadIdx.x;     // bi = z*4096 + i, 0..16383
    __shared__ float l5[32][5];
    __shared__ float lm[32];
    if(t < 32){
#pragma unroll
        for(int q = 0; q < 5; ++q) l5[t][q] = part5[((size_t)bi * 32 + t) * 5 + q];
        lm[t] = pmax[(size_t)bi * 32 + t];
    }
    __syncthreads();
    if(t == 0){
        float m5[5] = {FLTMAX, FLTMAX, FLTMAX, FLTMAX, FLTMAX};
        float mm = -FLTMAX;
        for(int c = 0; c < 32; ++c){
            mm = fmaxf(mm, lm[c]);
#pragma unroll
            for(int q = 0; q < 5; ++q) ins5(m5, l5[c][q]);
        }
        const float sqrtC = 22.627416997969522f;
        float s = 0.f;
#pragma unroll
        for(int q = 0; q < 5; ++q){
            float d = sqrtf(fmaxf(m5[q], 0.f)) / sqrtC;
            s = s + d * d;
        }
        dens_b[bi] = expf(-(s / 5.0f));
        atomicMax(dmax_b + (bi >> 12), __float_as_int(fmaxf(mm, 0.f)));
    }
}

// ---------- Pass B triangular, all batches ----------
__global__ __launch_bounds__(256) void gramB2(const float* Xb, const float* x2b,
                                              const float* dens_b, float* pmin){
    __shared__ float As[16][132];
    __shared__ float Bs[16][132];
    __shared__ float colbuf[16][129];
    int z = blockIdx.z;
    TRI_MAP((int)blockIdx.x, bi, bj)
    int i0 = bi * 128, j0 = bj * 128;
    int t = threadIdx.x, tx = t & 15, ty = t >> 4;
    const float* X = Xb + (size_t)z * 2097152;
    float acc[8][8] = {};
    GRAM2_CORE(X + (size_t)(i0 + ia) * 512, X + (size_t)(j0 + ia) * 512)
    float xj[8], dj[8];
#pragma unroll
    for(int u = 0; u < 8; ++u){
        int j = j0 + JLOC(u);
        xj[u] = x2b[(z << 12) + j];
        dj[u] = dens_b[(z << 12) + j];
    }
    // row pass -> slot [i][bj]
#pragma unroll
    for(int di = 0; di < 8; ++di){
        int i = i0 + (ty << 3) + di;
        float xi = x2b[(z << 12) + i];
        float deni = dens_b[(z << 12) + i];
        float pm = FLTMAX;
#pragma unroll
        for(int u = 0; u < 8; ++u){
            if(dj[u] > deni){
                float d2 = (xi + xj[u]) - 2.0f * acc[di][u];
                pm = fminf(pm, d2);
            }
        }
        for(int mk = 1; mk < 16; mk <<= 1)
            pm = fminf(pm, __shfl_xor(pm, mk));
        if(tx == 0) pmin[((size_t)(z << 12) + i) * 32 + bj] = pm;
    }
    // col pass (symmetry) -> slot [j][bi]
    if(bi != bj){
        float xi8[8], di8[8];
#pragma unroll
        for(int di = 0; di < 8; ++di){
            int i = i0 + (ty << 3) + di;
            xi8[di] = x2b[(z << 12) + i];
            di8[di] = dens_b[(z << 12) + i];
        }
        __syncthreads();
#pragma unroll
        for(int u = 0; u < 8; ++u){
            float denj = dj[u];
            float pm = FLTMAX;
#pragma unroll
            for(int di = 0; di < 8; ++di){
                if(di8[di] > denj){
                    float d2 = (xi8[di] + xj[u]) - 2.0f * acc[di][u];
                    pm = fminf(pm, d2);
                }
            }
            colbuf[ty][JLOC(u)] = pm;
        }
        __syncthreads();
        if(t < 128){
            float m = FLTMAX;
            for(int r = 0; r < 16; ++r) m = fminf(m, colbuf[r][t]);
            pmin[((size_t)(z << 12) + j0 + t) * 32 + bi] = m;
        }
    }
}

__global__ __launch_bounds__(64) void reduceB2(const float* pmin, const float* dens_b,
                                               const int* dmax_b, float* score_b){
    int bi = blockIdx.x, t = threadIdx.x;     // 0..16383
    __shared__ float lm[32];
    if(t < 32) lm[t] = pmin[(size_t)bi * 32 + t];
    __syncthreads();
    if(t == 0){
        float m = FLTMAX;
        for(int c = 0; c < 32; ++c) m = fminf(m, lm[c]);
        const float sqrtC = 22.627416997969522f;
        float dp;
        if(m == FLTMAX) dp = sqrtf(fmaxf(__int_as_float(dmax_b[bi >> 12]), 0.f)) / sqrtC;
        else            dp = sqrtf(fmaxf(m, 0.f)) / sqrtC;
        score_b[bi] = dp * dens_b[bi];
    }
}

// ---------- Pass C: gathered-center Gram -> per-(token, centerblock) argmin ----------
__global__ __launch_bounds__(256) void gramC2(const float* Xb, const float* x2b,
                                              const int* idown_b, float* pcd, int* pci){
    __shared__ float As[16][132];
    __shared__ float Bs[16][132];
    __shared__ float ldd[16][129];
    __shared__ int   ldi[16][129];
    int z = blockIdx.z;
    int s0 = blockIdx.y * 128, j0 = blockIdx.x * 128;
    int t = threadIdx.x, tx = t & 15, ty = t >> 4;
    const float* X = Xb + (size_t)z * 2097152;
    const int* idz = idown_b + (z << 10);
    float acc[8][8] = {};
    GRAM2_CORE(X + (size_t)idz[s0 + ia] * 512, X + (size_t)(j0 + ia) * 512)
    const float sqrtC = 22.627416997969522f;
    float xc[8];
#pragma unroll
    for(int di = 0; di < 8; ++di) xc[di] = x2b[(z << 12) + idz[s0 + (ty << 3) + di]];
#pragma unroll
    for(int u = 0; u < 8; ++u){
        int jl = JLOC(u);
        float xj = x2b[(z << 12) + j0 + jl];
        float bd = FLTMAX;
        int bs = 0;
#pragma unroll
        for(int di = 0; di < 8; ++di){           // di ascending => first-min ties stay first
            float d2 = (xc[di] + xj) - 2.0f * acc[di][u];
            float d = sqrtf(fmaxf(d2, 0.f)) / sqrtC;
            if(d < bd){ bd = d; bs = s0 + (ty << 3) + di; }
        }
        ldd[ty][jl] = bd;
        ldi[ty][jl] = bs;
    }
    __syncthreads();
    if(t < 128){
        float bd = FLTMAX;
        int bs = 0;
        for(int r = 0; r < 16; ++r){              // r ascending => center index ascending
            float d = ldd[r][t];
            if(d < bd){ bd = d; bs = ldi[r][t]; }
        }
        pcd[((size_t)(z << 12) + j0 + t) * 8 + blockIdx.y] = bd;
        pci[((size_t)(z << 12) + j0 + t) * 8 + blockIdx.y] = bs;
    }
}

__global__ void reduceC2(const float* pcd, const int* pci, int* iclus_b){
    int jg = blockIdx.x * 256 + threadIdx.x;      // 0..16383
    float bd = FLTMAX;
    int bs = 0;
    for(int c = 0; c < 8; ++c){
        float d = pcd[(size_t)jg * 8 + c];
        if(d < bd){ bd = d; bs = pci[(size_t)jg * 8 + c]; }
    }
    iclus_b[jg] = bs;
}

// ---------- bitonic sort (score desc, idx asc) -> top 1024; blockIdx.x = batch ----------
__global__ __launch_bounds__(1024) void sort_topk(const float* score, int* idown){
    __shared__ float ss[4096];
    __shared__ int sid[4096];
    int t = threadIdx.x;
    const float* sc = score + (size_t)blockIdx.x * 4096;
    int* id = idown + (size_t)blockIdx.x * 1024;
    for(int v = t; v < 4096; v += 1024){ ss[v] = sc[v]; sid[v] = v; }
    __syncthreads();
    for(int k = 2; k <= 4096; k <<= 1){
        for(int j = k >> 1; j > 0; j >>= 1){
            for(int v = t; v < 4096; v += 1024){
                int l = v ^ j;
                if(l > v){
                    float sv = ss[v], sl = ss[l];
                    int iv = sid[v], il = sid[l];
                    bool before_lv = (sl > sv) || (sl == sv && il < iv);
                    bool before_vl = (sv > sl) || (sv == sl && iv < il);
                    bool asc = ((v & k) == 0);
                    bool sw = asc ? before_lv : before_vl;
                    if(sw){ ss[v] = sl; ss[l] = sv; sid[v] = il; sid[l] = iv; }
                }
            }
            __syncthreads();
        }
    }
    for(int v = t; v < 1024; v += 1024) id[v] = sid[v];
}

// ---------- merge tokens + outputs (FLOAT32 out) ----------
__global__ void allw_add(const int* iclus, const float* wgt, float* allw){
    int e = blockIdx.x * 256 + threadIdx.x;   // 16384
    int b = e >> 12;
    unsafeAtomicAdd(&allw[(b << 10) + (iclus[e] & 1023)], wgt[e]);
}
__global__ void norm_k(const int* iclus, const float* wgt, const float* allw, float* nw){
    int e = blockIdx.x * 256 + threadIdx.x;
    int b = e >> 12;
    nw[e] = wgt[e] / allw[(b << 10) + (iclus[e] & 1023)];
}
__global__ void abuf_k(const int* idx_agg, const void* aggw, const float* nw,
                       float* abuf, float* maxw, const int* mode){
    int m = *mode;
    int e = blockIdx.x * 256 + threadIdx.x;
    int b = e >> 12;
    float a = ldin(aggw, e, m) * nw[(b << 12) + (idx_agg[e] & 4095)];
    abuf[e] = a;
    atomicMax((int*)&maxw[b], __float_as_int(a));
}
__global__ __launch_bounds__(128) void scatter_xdown(const int* iclus, const float* nw,
                                                     const float* xtok, float* xdown){
    int bn = blockIdx.x;           // 0..16383
    int b = bn >> 12;
    int cl = iclus[bn] & 1023;
    float w = nw[bn];
    const float* src = xtok + (size_t)bn * 512;
    float* dst = xdown + ((size_t)(b << 10) + cl) * 512;
    int c = threadIdx.x * 4;
    float4 v = *(const float4*)&src[c];
    unsafeAtomicAdd(&dst[c + 0], v.x * w);
    unsafeAtomicAdd(&dst[c + 1], v.y * w);
    unsafeAtomicAdd(&dst[c + 2], v.z * w);
    unsafeAtomicAdd(&dst[c + 3], v.w * w);
}

__global__ void out0_k(const float* xdown, float* out){
    int e = blockIdx.x * 256 + threadIdx.x;
    if(e < 2097152) out[e] = xdown[e];
}
__global__ void out1_k(const int* idx_agg, const int* iclus, float* out){
    int e = blockIdx.x * 256 + threadIdx.x;   // 16384
    int b = e >> 12;
    int ic = iclus[(b << 12) + (idx_agg[e] & 4095)];
    out[e] = (float)ic;
}
__global__ void out2_k(const float* abuf, const float* maxw, float* out){
    int e = blockIdx.x * 256 + threadIdx.x;
    int b = e >> 12;
    out[e] = abuf[e] / maxw[b];
}

// ---------- launch ----------
extern "C" void kernel_launch(void* const* d_in, const int* in_sizes, int n_in,
                              void* d_out, int out_size, void* d_ws, size_t ws_size,
                              hipStream_t stream){
    (void)in_sizes; (void)n_in; (void)out_size; (void)ws_size;
    const void* x    = d_in[0];
    const void* loc  = d_in[1];
    const int* idx_agg = (const int*)d_in[2];
    const void* aggw = d_in[3];
    const void* cw   = d_in[7];
    const void* cb   = d_in[8];
    const void* sw   = d_in[9];
    const void* lg   = d_in[10];
    const void* lnb  = d_in[11];
    const void* cfw  = d_in[12];
    const void* cfb  = d_in[13];
    float* out = (float*)d_out;

    // Flat alias-free layout: 20,848,649 floats = 83.4 MB (ws >= 101 MB proven in r7).
    float* ws    = (float*)d_ws;
    float* xtok  = ws;                      // 8,388,608
    float* xmap  = ws + 8388608;            // 4,194,304
    float* cnt   = ws + 12582912;           // 16,384
    float* convo = ws + 12599296;           // 2,097,152
    float* part5 = ws + 14696448;           // 2,621,440
    float* pmaxb = ws + 17317888;           // 524,288
    float* pminb = ws + 17842176;           // 524,288
    float* pcd   = ws + 18366464;           // 131,072
    int*   pci   = (int*)(ws + 18497536);   // 131,072
    float* xdown = ws + 18628608;           // 2,097,152
    float* x2    = ws + 20725760;           // 16,384
    float* wgt   = ws + 20742144;           // 16,384
    float* dens  = ws + 20758528;           // 16,384
    float* score = ws + 20774912;           // 16,384
    float* wsum  = ws + 20791296;           // 16,384
    float* allw  = ws + 20807680;           // 4,096
    float* nw    = ws + 20811776;           // 16,384
    float* dmaxf = ws + 20828160;           // 4
    float* maxw  = ws + 20828164;           // 4
    int*   idown = (int*)(ws + 20828168);   // 4,096
    int*   iclus = (int*)(ws + 20832264);   // 16,384
    int*   mode  = (int*)(ws + 20848648);   // 1

    detect_mode<<<1, 256, 0, stream>>>(x, mode);

    hipMemsetAsync(xmap, 0, (size_t)4194304 * 4, stream);
    hipMemsetAsync(cnt, 0, (size_t)16384 * 4, stream);
    hipMemsetAsync(dmaxf, 0, 8 * 4, stream);            // dmax[4] + maxw[4] adjacent
    hipMemsetAsync(xdown, 0, (size_t)2097152 * 4, stream);
    fill_f32<<<64, 256, 0, stream>>>(wsum, 1e-6f, 16384);
    fill_f32<<<16, 256, 0, stream>>>(allw, 1e-6f, 4096);

    scatter_map<<<16384, 256, 0, stream>>>(x, loc, idx_agg, xmap, cnt, mode);
    divide_map<<<16384, 256, 0, stream>>>(xmap, cnt, 4194304);

    init_convo<<<8192, 256, 0, stream>>>(convo, cb, mode);
    gemm_conv<<<dim3(4, 32, 8), 256, 0, stream>>>(xmap, cw, convo, mode);
    gemm_skip<<<dim3(8, 256), 256, 0, stream>>>(x, sw, xtok, mode);

    wsum_add<<<64, 256, 0, stream>>>(idx_agg, aggw, wsum, mode);
    scatter_tok<<<16384, 128, 0, stream>>>(loc, idx_agg, aggw, convo, wsum, xtok, mode);
    ln_conf<<<16384, 128, 0, stream>>>(xtok, lg, lnb, cfw, cfb, wgt, x2, mode);

    // ---- clustering: all 4 batches in one 7-launch chain ----
    gramA2<<<dim3(528, 1, 4), 256, 0, stream>>>(xtok, x2, part5, pmaxb);
    reduceA2<<<16384, 64, 0, stream>>>(part5, pmaxb, dens, (int*)dmaxf);
    gramB2<<<dim3(528, 1, 4), 256, 0, stream>>>(xtok, x2, dens, pminb);
    reduceB2<<<16384, 64, 0, stream>>>(pminb, dens, (int*)dmaxf, score);
    sort_topk<<<4, 1024, 0, stream>>>(score, idown);
    gramC2<<<dim3(32, 8, 4), 256, 0, stream>>>(xtok, x2, idown, pcd, pci);
    reduceC2<<<64, 256, 0, stream>>>(pcd, pci, iclus);

    allw_add<<<64, 256, 0, stream>>>(iclus, wgt, allw);
    norm_k<<<64, 256, 0, stream>>>(iclus, wgt, allw, nw);
    abuf_k<<<64, 256, 0, stream>>>(idx_agg, aggw, nw, score, maxw, mode);   // score reused as abuf

    scatter_xdown<<<16384, 128, 0, stream>>>(iclus, nw, xtok, xdown);

    out0_k<<<8192, 256, 0, stream>>>(xdown, out);
    out1_k<<<64, 256, 0, stream>>>(idx_agg, iclus, out + 2097152);
    out2_k<<<64, 256, 0, stream>>>(score, maxw, out + 2097152 + 16384);
}

// Round 10
// 2352.836 us; speedup vs baseline: 1.2095x; 1.0196x over previous
//
#include <hip/hip_runtime.h>

#define FLTMAX 3.402823466e+38f

// ---------- helpers ----------
__device__ inline float b2f(unsigned short u){
    return __uint_as_float(((unsigned int)u) << 16);
}
// flag-dispatched input load: mode=1 -> f32 buffer, mode=0 -> bf16 buffer
__device__ inline float ldin(const void* p, long i, int f32m){
    return f32m ? ((const float*)p)[i] : b2f(((const unsigned short*)p)[i]);
}
__device__ inline int pix_idx(float lx, float ly, float half, int wh){
    lx = fminf(fmaxf(lx, -1.f), 1.f);
    ly = fminf(fmaxf(ly, -1.f), 1.f);
    int px = (int)rintf((lx + 1.f) * half - 0.5f);   // round-half-even = jnp.round
    int py = (int)rintf((ly + 1.f) * half - 0.5f);
    px = min(max(px, 0), wh - 1);
    py = min(max(py, 0), wh - 1);
    return py * wh + px;
}
__device__ inline void ins5(float* b5, float d){
    if(d < b5[4]){
        b5[4] = d;
#pragma unroll
        for(int q = 4; q > 0; --q){
            if(b5[q] < b5[q-1]){ float tm = b5[q]; b5[q] = b5[q-1]; b5[q-1] = tm; }
        }
    }
}
__device__ inline float wred_add(float v){
    for(int o = 32; o > 0; o >>= 1) v += __shfl_down(v, o);
    return v;
}

// ---------- dtype auto-detect (64 blocks, atomic count; mode[0] = hit count) ----------
__global__ __launch_bounds__(256) void detect_mode(const void* xraw, int* flag){
    __shared__ int sh[256];
    const unsigned short* p = (const unsigned short*)xraw;
    int t = threadIdx.x, c = 0;
    int base = blockIdx.x * 1024;
    for(int i = base + t; i < base + 1024; i += 256){
        float v = b2f(p[i]);
        if(!(fabsf(v) < 100.f)) c++;
    }
    sh[t] = c;
    __syncthreads();
    for(int s = 128; s > 0; s >>= 1){
        if(t < s) sh[t] += sh[t + s];
        __syncthreads();
    }
    if(t == 0 && sh[0] > 0) atomicAdd(flag, sh[0]);
}
#define GETM(modeptr) (((*(modeptr)) > 64) ? 1 : 0)

// ---------- small utility kernels ----------
__global__ void fill_f32(float* p, float v, int n){
    int i = blockIdx.x * blockDim.x + threadIdx.x;
    if(i < n) p[i] = v;
}

// token2map scatter
__global__ __launch_bounds__(256) void scatter_map(const void* x, const void* loc,
                                                   const int* idx_agg, float* acc, float* cnt,
                                                   const int* mode){
    int m = GETM(mode);
    int bn = blockIdx.x;                 // 0..16383
    int b = bn >> 12;
    float lx = ldin(loc, (long)bn * 2 + 0, m);
    float ly = ldin(loc, (long)bn * 2 + 1, m);
    int p = pix_idx(lx, ly, 32.f, 64);
    int ia = idx_agg[bn] & 4095;
    long src = ((long)(b << 12) + ia) * 256;
    float* dst = acc + ((size_t)(b << 12) + p) * 256;
    int t = threadIdx.x;                 // 256 = C
    unsafeAtomicAdd(&dst[t], ldin(x, src + t, m));
    if(t == 0) unsafeAtomicAdd(&cnt[(b << 12) + p], 1.0f);
}

__global__ void divide_map(float* xmap, const float* cnt, int n){
    int i = blockIdx.x * 256 + threadIdx.x;
    if(i < n) xmap[i] = xmap[i] / (cnt[i >> 8] + 1e-6f);
}

// ---------- GEMM: skip  (x[16384,256] @ skip_w[256,512] -> xtok f32) ----------
__global__ __launch_bounds__(256) void gemm_skip(const void* A, const void* Bw, float* C,
                                                 const int* mode){
    int m = GETM(mode);
    __shared__ float As[16][68];
    __shared__ float Bs[16][68];
    int i0 = blockIdx.y * 64, j0 = blockIdx.x * 64;
    int t = threadIdx.x, tx = t & 15, ty = t >> 4;
    float acc[4][4] = {};
    for(int k0 = 0; k0 < 256; k0 += 16){
        int ia = t >> 2, kc = (t & 3) << 2;
#pragma unroll
        for(int u = 0; u < 4; ++u)
            As[kc+u][ia] = ldin(A, (long)(i0 + ia) * 256 + k0 + kc + u, m);
        int kb = t >> 4, jb = (t & 15) << 2;
        float4 bv;
        bv.x = ldin(Bw, (long)(k0 + kb) * 512 + j0 + jb + 0, m);
        bv.y = ldin(Bw, (long)(k0 + kb) * 512 + j0 + jb + 1, m);
        bv.z = ldin(Bw, (long)(k0 + kb) * 512 + j0 + jb + 2, m);
        bv.w = ldin(Bw, (long)(k0 + kb) * 512 + j0 + jb + 3, m);
        *(float4*)&Bs[kb][jb] = bv;
        __syncthreads();
#pragma unroll
        for(int kk = 0; kk < 16; ++kk){
            float4 a4 = *(const float4*)&As[kk][ty << 2];
            float4 b4 = *(const float4*)&Bs[kk][tx << 2];
            float ar[4] = {a4.x, a4.y, a4.z, a4.w};
            float br[4] = {b4.x, b4.y, b4.z, b4.w};
#pragma unroll
            for(int di = 0; di < 4; ++di)
#pragma unroll
                for(int dj = 0; dj < 4; ++dj)
                    acc[di][dj] = fmaf(ar[di], br[dj], acc[di][dj]);
        }
        __syncthreads();
    }
#pragma unroll
    for(int di = 0; di < 4; ++di){
        size_t i = i0 + (ty << 2) + di;
#pragma unroll
        for(int dj = 0; dj < 4; ++dj)
            C[i * 512 + j0 + (tx << 2) + dj] = acc[di][dj];
    }
}

// ---------- conv C init with bias ----------
__global__ void init_convo(float* convo, const void* bias, const int* mode){
    int m = GETM(mode);
    int e = blockIdx.x * 256 + threadIdx.x;   // 2,097,152
    convo[e] = ldin(bias, e & 511, m);
}

// ---------- conv3x3 s2 p1 via im2col: 128x128 tile, K-split x4, prefetch, atomic epilogue ----------
__global__ __launch_bounds__(256) void gemm_conv(const float* xmap, const void* Bw,
                                                 float* C, const int* mode){
    int m = GETM(mode);
    __shared__ float As[16][132];
    __shared__ float Bs[16][132];
    int i0 = blockIdx.y * 128, j0 = blockIdx.x * 128;
    int kz = blockIdx.z;                       // 0..3, K chunk of 576
    int t = threadIdx.x, tx = t & 15, ty = t >> 4;
    int ia = t >> 1, kc = (t & 1) << 3;        // it-invariant
    int p = i0 + ia;
    int b = p >> 10, r = p & 1023, oy = r >> 5, ox = r & 31;
    int kb = t >> 4, jb = (t & 15) << 3;
    float acc[8][8] = {};
    float4 v0, v1, w0, w1;
    // load it=0
    {
        int k0 = kz * 576;
        int f = k0 >> 8; int ky = f / 3, kx = f % 3; int c0 = k0 & 255;
        int iy = 2 * oy - 1 + ky, ix = 2 * ox - 1 + kx;
        v0 = make_float4(0.f,0.f,0.f,0.f); v1 = v0;
        if(iy >= 0 && iy < 64 && ix >= 0 && ix < 64){
            const float* src = &xmap[((size_t)(b << 12) + (iy << 6) + ix) * 256 + c0 + kc];
            v0 = *(const float4*)src; v1 = *(const float4*)(src + 4);
        }
        long bo = (long)(k0 + kb) * 512 + j0 + jb;
        w0.x = ldin(Bw, bo+0, m); w0.y = ldin(Bw, bo+1, m);
        w0.z = ldin(Bw, bo+2, m); w0.w = ldin(Bw, bo+3, m);
        w1.x = ldin(Bw, bo+4, m); w1.y = ldin(Bw, bo+5, m);
        w1.z = ldin(Bw, bo+6, m); w1.w = ldin(Bw, bo+7, m);
    }
    for(int it = 0; it < 36; ++it){
        As[kc+0][ia] = v0.x; As[kc+1][ia] = v0.y; As[kc+2][ia] = v0.z; As[kc+3][ia] = v0.w;
        As[kc+4][ia] = v1.x; As[kc+5][ia] = v1.y; As[kc+6][ia] = v1.z; As[kc+7][ia] = v1.w;
        *(float4*)&Bs[kb][jb] = w0;
        *(float4*)&Bs[kb][jb+4] = w1;
        if(it + 1 < 36){                      // prefetch it+1 before the barrier
            int k0 = kz * 576 + (it + 1) * 16;
            int f = k0 >> 8; int ky = f / 3, kx = f % 3; int c0 = k0 & 255;
            int iy = 2 * oy - 1 + ky, ix = 2 * ox - 1 + kx;
            v0 = make_float4(0.f,0.f,0.f,0.f); v1 = v0;
            if(iy >= 0 && iy < 64 && ix >= 0 && ix < 64){
                const float* src = &xmap[((size_t)(b << 12) + (iy << 6) + ix) * 256 + c0 + kc];
                v0 = *(const float4*)src; v1 = *(const float4*)(src + 4);
            }
            long bo = (long)(k0 + kb) * 512 + j0 + jb;
            w0.x = ldin(Bw, bo+0, m); w0.y = ldin(Bw, bo+1, m);
            w0.z = ldin(Bw, bo+2, m); w0.w = ldin(Bw, bo+3, m);
            w1.x = ldin(Bw, bo+4, m); w1.y = ldin(Bw, bo+5, m);
            w1.z = ldin(Bw, bo+6, m); w1.w = ldin(Bw, bo+7, m);
        }
        __syncthreads();
#pragma unroll
        for(int kk = 0; kk < 16; ++kk){
            float4 a0r = *(const float4*)&As[kk][ty << 3];
            float4 a1r = *(const float4*)&As[kk][(ty << 3) + 4];
            float4 b0r = *(const float4*)&Bs[kk][tx << 2];
            float4 b1r = *(const float4*)&Bs[kk][64 + (tx << 2)];
            float ar[8] = {a0r.x, a0r.y, a0r.z, a0r.w, a1r.x, a1r.y, a1r.z, a1r.w};
            float br[8] = {b0r.x, b0r.y, b0r.z, b0r.w, b1r.x, b1r.y, b1r.z, b1r.w};
#pragma unroll
            for(int di = 0; di < 8; ++di)
#pragma unroll
                for(int dj = 0; dj < 8; ++dj)
                    acc[di][dj] = fmaf(ar[di], br[dj], acc[di][dj]);
        }
        __syncthreads();
    }
#pragma unroll
    for(int di = 0; di < 8; ++di){
        size_t i = i0 + (ty << 3) + di;
#pragma unroll
        for(int u = 0; u < 4; ++u){
            unsafeAtomicAdd(&C[i * 512 + j0 + (tx << 2) + u], acc[di][u]);
            unsafeAtomicAdd(&C[i * 512 + j0 + 64 + (tx << 2) + u], acc[di][4 + u]);
        }
    }
}

// ---------- map2token ----------
__global__ void wsum_add(const int* idx_agg, const void* aggw, float* wsum, const int* mode){
    int m = GETM(mode);
    int e = blockIdx.x * 256 + threadIdx.x;   // 16384
    int b = e >> 12;
    unsafeAtomicAdd(&wsum[(b << 12) + (idx_agg[e] & 4095)], ldin(aggw, e, m));
}

__global__ __launch_bounds__(128) void scatter_tok(const void* loc, const int* idx_agg,
                                                   const void* aggw, const float* convo,
                                                   const float* wsum, float* xtok, const int* mode){
    int m = GETM(mode);
    int bn = blockIdx.x;
    int b = bn >> 12;
    float lx = ldin(loc, (long)bn * 2 + 0, m);
    float ly = ldin(loc, (long)bn * 2 + 1, m);
    int p = pix_idx(lx, ly, 16.f, 32);
    int tk = idx_agg[bn] & 4095;
    float w = ldin(aggw, bn, m);
    float scale = w / wsum[(b << 12) + tk];
    const float* pv = convo + ((size_t)(b << 10) + p) * 512;
    float* dst = xtok + ((size_t)(b << 12) + tk) * 512;
    int c = threadIdx.x * 4;
    float4 v = *(const float4*)&pv[c];
    unsafeAtomicAdd(&dst[c + 0], v.x * scale);
    unsafeAtomicAdd(&dst[c + 1], v.y * scale);
    unsafeAtomicAdd(&dst[c + 2], v.z * scale);
    unsafeAtomicAdd(&dst[c + 3], v.w * scale);
}

// ---------- fused layernorm + conf + weight + x2 ----------
__global__ __launch_bounds__(128) void ln_conf(float* xtok, const void* g_, const void* b_,
                                               const void* cw_, const void* cb_,
                                               float* wgt, float* x2a, const int* mode){
    int m = GETM(mode);
    int row = blockIdx.x;        // 0..16383
    int t = threadIdx.x;         // 128
    float* xr = xtok + (size_t)row * 512;
    int c0 = t * 4;
    float4 v = *(const float4*)&xr[c0];
    float xv[4] = {v.x, v.y, v.z, v.w};
    __shared__ float red[2];
    __shared__ float red2[4];
    float s = xv[0] + xv[1] + xv[2] + xv[3];
    s = wred_add(s);
    if((t & 63) == 0) red[t >> 6] = s;
    __syncthreads();
    float mean = (red[0] + red[1]) * (1.f / 512.f);
    __syncthreads();
    float xc[4];
#pragma unroll
    for(int u = 0; u < 4; ++u) xc[u] = xv[u] - mean;
    float q = xc[0]*xc[0] + xc[1]*xc[1] + xc[2]*xc[2] + xc[3]*xc[3];
    q = wred_add(q);
    if((t & 63) == 0) red[t >> 6] = q;
    __syncthreads();
    float var = (red[0] + red[1]) * (1.f / 512.f);
    float rs = 1.0f / sqrtf(var + 1e-5f);
    float y[4];
#pragma unroll
    for(int u = 0; u < 4; ++u)
        y[u] = xc[u] * rs * ldin(g_, c0 + u, m) + ldin(b_, c0 + u, m);
    float4 st; st.x = y[0]; st.y = y[1]; st.z = y[2]; st.w = y[3];
    *(float4*)&xr[c0] = st;
    float cf = y[0]*ldin(cw_, c0+0, m) + y[1]*ldin(cw_, c0+1, m)
             + y[2]*ldin(cw_, c0+2, m) + y[3]*ldin(cw_, c0+3, m);
    float qq = y[0]*y[0] + y[1]*y[1] + y[2]*y[2] + y[3]*y[3];
    cf = wred_add(cf);
    qq = wred_add(qq);
    if((t & 63) == 0){ red2[t >> 6] = cf; red2[2 + (t >> 6)] = qq; }
    __syncthreads();
    if(t == 0){
        wgt[row] = expf(red2[0] + red2[1] + ldin(cb_, 0, m));
        x2a[row] = red2[2] + red2[3];
    }
}

// ---------- Gram staging + MAC (r8 version — no prefetch) ----------
#define GRAM2_CORE(AROWPTR, BROWPTR)                                               \
    for(int k0 = 0; k0 < 512; k0 += 16){                                           \
        int ia = t >> 1, kc = (t & 1) << 3;                                        \
        const float* ap = (AROWPTR) + k0 + kc;                                     \
        float4 a0 = *(const float4*)ap;                                            \
        float4 a1 = *(const float4*)(ap + 4);                                      \
        As[kc+0][ia] = a0.x; As[kc+1][ia] = a0.y; As[kc+2][ia] = a0.z; As[kc+3][ia] = a0.w; \
        As[kc+4][ia] = a1.x; As[kc+5][ia] = a1.y; As[kc+6][ia] = a1.z; As[kc+7][ia] = a1.w; \
        const float* bp = (BROWPTR) + k0 + kc;                                     \
        float4 b0 = *(const float4*)bp;                                            \
        float4 b1 = *(const float4*)(bp + 4);                                      \
        Bs[kc+0][ia] = b0.x; Bs[kc+1][ia] = b0.y; Bs[kc+2][ia] = b0.z; Bs[kc+3][ia] = b0.w; \
        Bs[kc+4][ia] = b1.x; Bs[kc+5][ia] = b1.y; Bs[kc+6][ia] = b1.z; Bs[kc+7][ia] = b1.w; \
        __syncthreads();                                                           \
        for(int kk = 0; kk < 16; ++kk){                                            \
            float4 a0r = *(const float4*)&As[kk][ty << 3];                         \
            float4 a1r = *(const float4*)&As[kk][(ty << 3) + 4];                   \
            float4 b0r = *(const float4*)&Bs[kk][tx << 2];                         \
            float4 b1r = *(const float4*)&Bs[kk][64 + (tx << 2)];                  \
            float ar[8] = {a0r.x, a0r.y, a0r.z, a0r.w, a1r.x, a1r.y, a1r.z, a1r.w};\
            float br[8] = {b0r.x, b0r.y, b0r.z, b0r.w, b1r.x, b1r.y, b1r.z, b1r.w};\
            for(int di = 0; di < 8; ++di)                                          \
                for(int dj = 0; dj < 8; ++dj)                                      \
                    acc[di][dj] = fmaf(ar[di], br[dj], acc[di][dj]);               \
        }                                                                          \
        __syncthreads();                                                           \
    }

// local j of slot u (u 0..7)
#define JLOC(u) (((u) < 4) ? ((tx << 2) + (u)) : (64 + (tx << 2) + (u) - 4))

// triangular block map: q -> (bi <= bj)
#define TRI_MAP(q, bi, bj)                                         \
    int bj = (int)((sqrtf(8.0f * (q) + 1.0f) - 1.0f) * 0.5f);      \
    while((bj + 1) * (bj + 2) / 2 <= (q)) bj++;                    \
    while(bj * (bj + 1) / 2 > (q)) bj--;                           \
    int bi = (q) - bj * (bj + 1) / 2;

// ---------- Pass A triangular, all batches (z = batch) ----------
__global__ __launch_bounds__(256) void gramA2(const float* Xb, const float* x2b,
                                              float* part5, float* pmax){
    __shared__ float As[16][132];
    __shared__ float Bs[16][132];
    __shared__ float sbuf[2176];          // row pass: [128][17]; col pass: [16][129]
    int z = blockIdx.z;
    TRI_MAP((int)blockIdx.x, bi, bj)
    int i0 = bi * 128, j0 = bj * 128;
    int t = threadIdx.x, tx = t & 15, ty = t >> 4;
    const float* X = Xb + (size_t)z * 2097152;
    float acc[8][8] = {};
    GRAM2_CORE(X + (size_t)(i0 + ia) * 512, X + (size_t)(j0 + ia) * 512)
    float xj[8];
#pragma unroll
    for(int u = 0; u < 8; ++u) xj[u] = x2b[(z << 12) + j0 + JLOC(u)];
    // ---- row pass: local top5-of-8 per di, then LDS metric-merge across tx ----
    float lb5[8][5];
    float lmx[8];
#pragma unroll
    for(int di = 0; di < 8; ++di){
        int i = i0 + (ty << 3) + di;
        float xi = x2b[(z << 12) + i];
        lb5[di][0] = FLTMAX; lb5[di][1] = FLTMAX; lb5[di][2] = FLTMAX;
        lb5[di][3] = FLTMAX; lb5[di][4] = FLTMAX;
        lmx[di] = -FLTMAX;
#pragma unroll
        for(int u = 0; u < 8; ++u){
            float d2 = (xi + xj[u]) - 2.0f * acc[di][u];
            ins5(lb5[di], d2);
            lmx[di] = fmaxf(lmx[di], d2);
        }
    }
    float m5r[5] = {FLTMAX, FLTMAX, FLTMAX, FLTMAX, FLTMAX};
    float mmr = -FLTMAX;
#pragma unroll
    for(int met = 0; met < 6; ++met){
        __syncthreads();
#pragma unroll
        for(int di = 0; di < 8; ++di)
            sbuf[((ty << 3) + di) * 17 + tx] = (met < 5) ? lb5[di][met] : lmx[di];
        __syncthreads();
        if(t < 128){
            if(met < 5){
                for(int c = 0; c < 16; ++c) ins5(m5r, sbuf[t * 17 + c]);
            } else {
                for(int c = 0; c < 16; ++c) mmr = fmaxf(mmr, sbuf[t * 17 + c]);
            }
        }
    }
    if(t < 128){
        size_t row = (size_t)(z << 12) + i0 + t;
        size_t o = (row * 32 + bj) * 5;
#pragma unroll
        for(int q = 0; q < 5; ++q) part5[o + q] = m5r[q];
        pmax[row * 32 + bj] = mmr;
    }
    // ---- col pass (symmetry) -> slot [j][bi]; diagonal tiles skip ----
    if(bi != bj){
        float xi8[8];
#pragma unroll
        for(int di = 0; di < 8; ++di) xi8[di] = x2b[(z << 12) + i0 + (ty << 3) + di];
        float c5[8][5];
        float cm[8];
#pragma unroll
        for(int u = 0; u < 8; ++u){
            c5[u][0] = FLTMAX; c5[u][1] = FLTMAX; c5[u][2] = FLTMAX;
            c5[u][3] = FLTMAX; c5[u][4] = FLTMAX;
            cm[u] = -FLTMAX;
#pragma unroll
            for(int di = 0; di < 8; ++di){
                float d2 = (xi8[di] + xj[u]) - 2.0f * acc[di][u];
                ins5(c5[u], d2);
                cm[u] = fmaxf(cm[u], d2);
            }
        }
        float m5[5] = {FLTMAX, FLTMAX, FLTMAX, FLTMAX, FLTMAX};
        float mm = -FLTMAX;
#pragma unroll
        for(int met = 0; met < 6; ++met){
            __syncthreads();
#pragma unroll
            for(int u = 0; u < 8; ++u)
                sbuf[ty * 129 + JLOC(u)] = (met < 5) ? c5[u][met] : cm[u];
            __syncthreads();
            if(t < 128){
                if(met < 5){
                    for(int r = 0; r < 16; ++r) ins5(m5, sbuf[r * 129 + t]);
                } else {
                    for(int r = 0; r < 16; ++r) mm = fmaxf(mm, sbuf[r * 129 + t]);
                }
            }
        }
        if(t < 128){
            size_t row = (size_t)(z << 12) + j0 + t;
            size_t o = (row * 32 + bi) * 5;
#pragma unroll
            for(int q = 0; q < 5; ++q) part5[o + q] = m5[q];
            pmax[row * 32 + bi] = mm;
        }
    }
}

__global__ __launch_bounds__(64) void reduceA2(const float* part5, const float* pmax,
                                               float* dens_b, int* dmax_b){
    int bi = blockIdx.x, t = threadIdx.x;     // bi = z*4096 + i, 0..16383
    __shared__ float l5[32][5];
    __shared__ float lm[32];
    if(t < 32){
#pragma unroll
        for(int q = 0; q < 5; ++q) l5[t][q] = part5[((size_t)bi * 32 + t) * 5 + q];
        lm[t] = pmax[(size_t)bi * 32 + t];
    }
    __syncthreads();
    if(t == 0){
        float m5[5] = {FLTMAX, FLTMAX, FLTMAX, FLTMAX, FLTMAX};
        float mm = -FLTMAX;
        for(int c = 0; c < 32; ++c){
            mm = fmaxf(mm, lm[c]);
#pragma unroll
            for(int q = 0; q < 5; ++q) ins5(m5, l5[c][q]);
        }
        const float sqrtC = 22.627416997969522f;
        float s = 0.f;
#pragma unroll
        for(int q = 0; q < 5; ++q){
            float d = sqrtf(fmaxf(m5[q], 0.f)) / sqrtC;
            s = s + d * d;
        }
        dens_b[bi] = expf(-(s / 5.0f));
        atomicMax(dmax_b + (bi >> 12), __float_as_int(fmaxf(mm, 0.f)));
    }
}

// ---------- Pass B triangular, all batches ----------
__global__ __launch_bounds__(256) void gramB2(const float* Xb, const float* x2b,
                                              const float* dens_b, float* pmin){
    __shared__ float As[16][132];
    __shared__ float Bs[16][132];
    __shared__ float colbuf[16][129];
    int z = blockIdx.z;
    TRI_MAP((int)blockIdx.x, bi, bj)
    int i0 = bi * 128, j0 = bj * 128;
    int t = threadIdx.x, tx = t & 15, ty = t >> 4;
    const float* X = Xb + (size_t)z * 2097152;
    float acc[8][8] = {};
    GRAM2_CORE(X + (size_t)(i0 + ia) * 512, X + (size_t)(j0 + ia) * 512)
    float xj[8], dj[8];
#pragma unroll
    for(int u = 0; u < 8; ++u){
        int j = j0 + JLOC(u);
        xj[u] = x2b[(z << 12) + j];
        dj[u] = dens_b[(z << 12) + j];
    }
    // row pass -> slot [i][bj]
#pragma unroll
    for(int di = 0; di < 8; ++di){
        int i = i0 + (ty << 3) + di;
        float xi = x2b[(z << 12) + i];
        float deni = dens_b[(z << 12) + i];
        float pm = FLTMAX;
#pragma unroll
        for(int u = 0; u < 8; ++u){
            if(dj[u] > deni){
                float d2 = (xi + xj[u]) - 2.0f * acc[di][u];
                pm = fminf(pm, d2);
            }
        }
        for(int mk = 1; mk < 16; mk <<= 1)
            pm = fminf(pm, __shfl_xor(pm, mk));
        if(tx == 0) pmin[((size_t)(z << 12) + i) * 32 + bj] = pm;
    }
    // col pass (symmetry) -> slot [j][bi]
    if(bi != bj){
        float xi8[8], di8[8];
#pragma unroll
        for(int di = 0; di < 8; ++di){
            int i = i0 + (ty << 3) + di;
            xi8[di] = x2b[(z << 12) + i];
            di8[di] = dens_b[(z << 12) + i];
        }
        __syncthreads();
#pragma unroll
        for(int u = 0; u < 8; ++u){
            float denj = dj[u];
            float pm = FLTMAX;
#pragma unroll
            for(int di = 0; di < 8; ++di){
                if(di8[di] > denj){
                    float d2 = (xi8[di] + xj[u]) - 2.0f * acc[di][u];
                    pm = fminf(pm, d2);
                }
            }
            colbuf[ty][JLOC(u)] = pm;
        }
        __syncthreads();
        if(t < 128){
            float m = FLTMAX;
            for(int r = 0; r < 16; ++r) m = fminf(m, colbuf[r][t]);
            pmin[((size_t)(z << 12) + j0 + t) * 32 + bi] = m;
        }
    }
}

__global__ __launch_bounds__(64) void reduceB2(const float* pmin, const float* dens_b,
                                               const int* dmax_b, float* score_b){
    int bi = blockIdx.x, t = threadIdx.x;     // 0..16383
    __shared__ float lm[32];
    if(t < 32) lm[t] = pmin[(size_t)bi * 32 + t];
    __syncthreads();
    if(t == 0){
        float m = FLTMAX;
        for(int c = 0; c < 32; ++c) m = fminf(m, lm[c]);
        const float sqrtC = 22.627416997969522f;
        float dp;
        if(m == FLTMAX) dp = sqrtf(fmaxf(__int_as_float(dmax_b[bi >> 12]), 0.f)) / sqrtC;
        else            dp = sqrtf(fmaxf(m, 0.f)) / sqrtC;
        score_b[bi] = dp * dens_b[bi];
    }
}

// ---------- Pass C: gathered-center Gram -> per-(token, centerblock) argmin ----------
__global__ __launch_bounds__(256) void gramC2(const float* Xb, const float* x2b,
                                              const int* idown_b, float* pcd, int* pci){
    __shared__ float As[16][132];
    __shared__ float Bs[16][132];
    __shared__ float ldd[16][129];
    __shared__ int   ldi[16][129];
    int z = blockIdx.z;
    int s0 = blockIdx.y * 128, j0 = blockIdx.x * 128;
    int t = threadIdx.x, tx = t & 15, ty = t >> 4;
    const float* X = Xb + (size_t)z * 2097152;
    const int* idz = idown_b + (z << 10);
    float acc[8][8] = {};
    GRAM2_CORE(X + (size_t)idz[s0 + ia] * 512, X + (size_t)(j0 + ia) * 512)
    const float sqrtC = 22.627416997969522f;
    float xc[8];
#pragma unroll
    for(int di = 0; di < 8; ++di) xc[di] = x2b[(z << 12) + idz[s0 + (ty << 3) + di]];
#pragma unroll
    for(int u = 0; u < 8; ++u){
        int jl = JLOC(u);
        float xj = x2b[(z << 12) + j0 + jl];
        float bd = FLTMAX;
        int bs = 0;
#pragma unroll
        for(int di = 0; di < 8; ++di){           // di ascending => first-min ties stay first
            float d2 = (xc[di] + xj) - 2.0f * acc[di][u];
            float d = sqrtf(fmaxf(d2, 0.f)) / sqrtC;
            if(d < bd){ bd = d; bs = s0 + (ty << 3) + di; }
        }
        ldd[ty][jl] = bd;
        ldi[ty][jl] = bs;
    }
    __syncthreads();
    if(t < 128){
        float bd = FLTMAX;
        int bs = 0;
        for(int r = 0; r < 16; ++r){              // r ascending => center index ascending
            float d = ldd[r][t];
            if(d < bd){ bd = d; bs = ldi[r][t]; }
        }
        pcd[((size_t)(z << 12) + j0 + t) * 8 + blockIdx.y] = bd;
        pci[((size_t)(z << 12) + j0 + t) * 8 + blockIdx.y] = bs;
    }
}

__global__ void reduceC2(const float* pcd, const int* pci, int* iclus_b){
    int jg = blockIdx.x * 256 + threadIdx.x;      // 0..16383
    float bd = FLTMAX;
    int bs = 0;
    for(int c = 0; c < 8; ++c){
        float d = pcd[(size_t)jg * 8 + c];
        if(d < bd){ bd = d; bs = pci[(size_t)jg * 8 + c]; }
    }
    iclus_b[jg] = bs;
}

// ---------- bitonic sort (score desc, idx asc) -> top 1024; blockIdx.x = batch ----------
__global__ __launch_bounds__(1024) void sort_topk(const float* score, int* idown){
    __shared__ float ss[4096];
    __shared__ int sid[4096];
    int t = threadIdx.x;
    const float* sc = score + (size_t)blockIdx.x * 4096;
    int* id = idown + (size_t)blockIdx.x * 1024;
    for(int v = t; v < 4096; v += 1024){ ss[v] = sc[v]; sid[v] = v; }
    __syncthreads();
    for(int k = 2; k <= 4096; k <<= 1){
        for(int j = k >> 1; j > 0; j >>= 1){
            for(int v = t; v < 4096; v += 1024){
                int l = v ^ j;
                if(l > v){
                    float sv = ss[v], sl = ss[l];
                    int iv = sid[v], il = sid[l];
                    bool before_lv = (sl > sv) || (sl == sv && il < iv);
                    bool before_vl = (sv > sl) || (sv == sl && iv < il);
                    bool asc = ((v & k) == 0);
                    bool sw = asc ? before_lv : before_vl;
                    if(sw){ ss[v] = sl; ss[l] = sv; sid[v] = il; sid[l] = iv; }
                }
            }
            __syncthreads();
        }
    }
    for(int v = t; v < 1024; v += 1024) id[v] = sid[v];
}

// ---------- merge tokens + outputs (FLOAT32 out) ----------
__global__ void allw_add(const int* iclus, const float* wgt, float* allw){
    int e = blockIdx.x * 256 + threadIdx.x;   // 16384
    int b = e >> 12;
    unsafeAtomicAdd(&allw[(b << 10) + (iclus[e] & 1023)], wgt[e]);
}
__global__ void norm_k(const int* iclus, const float* wgt, const float* allw, float* nw){
    int e = blockIdx.x * 256 + threadIdx.x;
    int b = e >> 12;
    nw[e] = wgt[e] / allw[(b << 10) + (iclus[e] & 1023)];
}
__global__ void abuf_k(const int* idx_agg, const void* aggw, const float* nw,
                       float* abuf, float* maxw, const int* mode){
    int m = GETM(mode);
    int e = blockIdx.x * 256 + threadIdx.x;
    int b = e >> 12;
    float a = ldin(aggw, e, m) * nw[(b << 12) + (idx_agg[e] & 4095)];
    abuf[e] = a;
    atomicMax((int*)&maxw[b], __float_as_int(a));
}
__global__ __launch_bounds__(128) void scatter_xdown(const int* iclus, const float* nw,
                                                     const float* xtok, float* xdown){
    int bn = blockIdx.x;           // 0..16383
    int b = bn >> 12;
    int cl = iclus[bn] & 1023;
    float w = nw[bn];
    const float* src = xtok + (size_t)bn * 512;
    float* dst = xdown + ((size_t)(b << 10) + cl) * 512;
    int c = threadIdx.x * 4;
    float4 v = *(const float4*)&src[c];
    unsafeAtomicAdd(&dst[c + 0], v.x * w);
    unsafeAtomicAdd(&dst[c + 1], v.y * w);
    unsafeAtomicAdd(&dst[c + 2], v.z * w);
    unsafeAtomicAdd(&dst[c + 3], v.w * w);
}

__global__ void out0_k(const float* xdown, float* out){
    int e = blockIdx.x * 256 + threadIdx.x;
    if(e < 2097152) out[e] = xdown[e];
}
// fused out1 + out2 (both 16384-elem)
__global__ void out12_k(const int* idx_agg, const int* iclus, const float* abuf,
                        const float* maxw, float* out){
    int e = blockIdx.x * 256 + threadIdx.x;   // 16384
    int b = e >> 12;
    int ic = iclus[(b << 12) + (idx_agg[e] & 4095)];
    out[2097152 + e] = (float)ic;
    out[2097152 + 16384 + e] = abuf[e] / maxw[b];
}

// ---------- launch ----------
extern "C" void kernel_launch(void* const* d_in, const int* in_sizes, int n_in,
                              void* d_out, int out_size, void* d_ws, size_t ws_size,
                              hipStream_t stream){
    (void)in_sizes; (void)n_in; (void)out_size; (void)ws_size;
    const void* x    = d_in[0];
    const void* loc  = d_in[1];
    const int* idx_agg = (const int*)d_in[2];
    const void* aggw = d_in[3];
    const void* cw   = d_in[7];
    const void* cb   = d_in[8];
    const void* sw   = d_in[9];
    const void* lg   = d_in[10];
    const void* lnb  = d_in[11];
    const void* cfw  = d_in[12];
    const void* cfb  = d_in[13];
    float* out = (float*)d_out;

    // Flat alias-free layout: 20,848,649 floats = 83.4 MB (ws >= 101 MB proven in r7).
    float* ws    = (float*)d_ws;
    float* xtok  = ws;                      // 8,388,608
    float* xmap  = ws + 8388608;            // 4,194,304
    float* cnt   = ws + 12582912;           // 16,384 (adjacent to xmap)
    float* convo = ws + 12599296;           // 2,097,152
    float* part5 = ws + 14696448;           // 2,621,440
    float* pmaxb = ws + 17317888;           // 524,288
    float* pminb = ws + 17842176;           // 524,288
    float* pcd   = ws + 18366464;           // 131,072
    int*   pci   = (int*)(ws + 18497536);   // 131,072
    float* xdown = ws + 18628608;           // 2,097,152
    float* x2    = ws + 20725760;           // 16,384
    float* wgt   = ws + 20742144;           // 16,384
    float* dens  = ws + 20758528;           // 16,384
    float* score = ws + 20774912;           // 16,384
    float* wsum  = ws + 20791296;           // 16,384
    float* allw  = ws + 20807680;           // 4,096 (adjacent to wsum)
    float* nw    = ws + 20811776;           // 16,384
    float* dmaxf = ws + 20828160;           // 4
    float* maxw  = ws + 20828164;           // 4
    int*   idown = (int*)(ws + 20828168);   // 4,096
    int*   iclus = (int*)(ws + 20832264);   // 16,384
    int*   mode  = (int*)(ws + 20848648);   // 1 (hit count)

    hipMemsetAsync(mode, 0, 4, stream);
    detect_mode<<<64, 256, 0, stream>>>(x, mode);

    hipMemsetAsync(xmap, 0, (size_t)(4194304 + 16384) * 4, stream);  // xmap + cnt (adjacent)
    hipMemsetAsync(dmaxf, 0, 8 * 4, stream);                         // dmax[4] + maxw[4]
    hipMemsetAsync(xdown, 0, (size_t)2097152 * 4, stream);
    fill_f32<<<80, 256, 0, stream>>>(wsum, 1e-6f, 20480);            // wsum + allw (adjacent)

    scatter_map<<<16384, 256, 0, stream>>>(x, loc, idx_agg, xmap, cnt, mode);
    divide_map<<<16384, 256, 0, stream>>>(xmap, cnt, 4194304);

    init_convo<<<8192, 256, 0, stream>>>(convo, cb, mode);
    gemm_conv<<<dim3(4, 32, 4), 256, 0, stream>>>(xmap, cw, convo, mode);
    gemm_skip<<<dim3(8, 256), 256, 0, stream>>>(x, sw, xtok, mode);

    wsum_add<<<64, 256, 0, stream>>>(idx_agg, aggw, wsum, mode);
    scatter_tok<<<16384, 128, 0, stream>>>(loc, idx_agg, aggw, convo, wsum, xtok, mode);
    ln_conf<<<16384, 128, 0, stream>>>(xtok, lg, lnb, cfw, cfb, wgt, x2, mode);

    // ---- clustering: all 4 batches in one 7-launch chain ----
    gramA2<<<dim3(528, 1, 4), 256, 0, stream>>>(xtok, x2, part5, pmaxb);
    reduceA2<<<16384, 64, 0, stream>>>(part5, pmaxb, dens, (int*)dmaxf);
    gramB2<<<dim3(528, 1, 4), 256, 0, stream>>>(xtok, x2, dens, pminb);
    reduceB2<<<16384, 64, 0, stream>>>(pminb, dens, (int*)dmaxf, score);
    sort_topk<<<4, 1024, 0, stream>>>(score, idown);
    gramC2<<<dim3(32, 8, 4), 256, 0, stream>>>(xtok, x2, idown, pcd, pci);
    reduceC2<<<64, 256, 0, stream>>>(pcd, pci, iclus);

    allw_add<<<64, 256, 0, stream>>>(iclus, wgt, allw);
    norm_k<<<64, 256, 0, stream>>>(iclus, wgt, allw, nw);
    abuf_k<<<64, 256, 0, stream>>>(idx_agg, aggw, nw, score, maxw, mode);   // score reused as abuf

    scatter_xdown<<<16384, 128, 0, stream>>>(iclus, nw, xtok, xdown);

    out0_k<<<8192, 256, 0, stream>>>(xdown, out);
    out12_k<<<64, 256, 0, stream>>>(idx_agg, iclus, score, maxw, out);
}